// Round 5
// baseline (4642.172 us; speedup 1.0000x reference)
//
#include <hip/hip_runtime.h>
#include <hip/hip_bf16.h>
#include <math.h>

typedef __attribute__((ext_vector_type(4))) float fvec4;
typedef __attribute__((ext_vector_type(2))) float fvec2;
typedef __attribute__((ext_vector_type(4))) int ivec4;
typedef __attribute__((ext_vector_type(4))) unsigned short usvec4;
typedef __attribute__((ext_vector_type(8))) short bf16x8;

#define SEQ 2048
#define DMODEL 2048
#define DINNER 4096
#define DSTATE 16
#define DTRANK 128
#define NB 4
#define MROWS (NB*SEQ)  // 8192
#define NCHUNK 16
#define LC (SEQ/NCHUNK) // 128

__device__ __forceinline__ float bf2f(unsigned short h){
  union{unsigned int u; float f;} v; v.u = ((unsigned int)h)<<16; return v.f;
}
__device__ __forceinline__ unsigned short f2bf(float f){
  union{float f; unsigned int u;} v; v.f=f;
  unsigned int r = v.u + 0x7fffu + ((v.u>>16)&1u);
  return (unsigned short)(r>>16);
}
__device__ __forceinline__ void async16(const void* g, void* l){
  __builtin_amdgcn_global_load_lds((const __attribute__((address_space(1))) void*)g,
                                   (__attribute__((address_space(3))) void*)l, 16, 0, 0);
}
__device__ __forceinline__ float sigf(float x){ return 1.f/(1.f+__expf(-x)); }

// ---------------- fp32 -> bf16 convert ----------------
__global__ void cvt_bf16_kernel(const float* __restrict__ in, unsigned short* __restrict__ out, int n){
  int i = (blockIdx.x*256 + threadIdx.x)*4;
  if (i >= n) return;
  fvec4 v = *(const fvec4*)(in + i);
  usvec4 o;
  o[0]=f2bf(v[0]); o[1]=f2bf(v[1]); o[2]=f2bf(v[2]); o[3]=f2bf(v[3]);
  *(usvec4*)(out + i) = o;
}

// ================= 256x256 GEMM (C = A * B^T), 2-slot ring =================
// BK=32, 2-slot LDS ring (64 KiB -> 2 blocks/CU), ONE barrier per K-step:
//   [vmcnt(0): my 4 loads for tile kt done] -> [s_barrier: everyone staged kt,
//   everyone's reads of the other slot done] -> [stage kt+1 into other slot]
//   -> [read slot kt, MFMA].
// Race-free: a slot is re-staged only after the barrier FOLLOWING the iteration
// that read it. Stage->wait distance = one full compute phase (~1100cy > HBM).
// T2 swizzle: slot s=(fr>>1)&3 -> each 16-lane group covers all 8 LDS 16B-slots
// exactly twice (2-way, free). Same involution pre-applied to global source.
// T1 XCD swizzle. 8 waves (2M x 4N), wave tile 128x64.
// MODE 0: split x/z bf16 at col 4096 (in_proj). MODE 3: fp32 store (out_proj).
template<int MODE>
__global__ __launch_bounds__(512, 4) void gemm256(
    const unsigned short* __restrict__ A,
    const unsigned short* __restrict__ B,
    int K, int nbx, int ldc,
    unsigned short* __restrict__ Cb1,
    unsigned short* __restrict__ Cb2,
    float* __restrict__ Cf)
{
  __shared__ __align__(16) unsigned short lds[32768];  // 2 slots x 32 KiB
  char* ldsc = (char*)lds;
  const int t = threadIdx.x;

  // T1: XCD swizzle (gridDim.x % 8 == 0 for all uses)
  const int nwg = gridDim.x;
  const int cpx = nwg >> 3;
  const int bid = blockIdx.x;
  const int swzb = (bid & 7)*cpx + (bid >> 3);
  const int bx = swzb % nbx, by = swzb / nbx;

  // staging source: pre-apply the LDS swizzle involution to the global source
  // byte ^= ((byte>>7)&3)<<4  (within each operand's 16 KiB region)
  const int bA0 = t*16, bA1 = 8192 + t*16;
  const int sw0 = bA0 ^ (((bA0>>7)&3)<<4);
  const int sw1 = bA1 ^ (((bA1>>7)&3)<<4);
  const int gr0 = sw0>>6, gc0 = (sw0&63)>>1;
  const int gr1 = sw1>>6, gc1 = (sw1&63)>>1;
  const unsigned short* Ab = A + (long)by*256*K;
  const unsigned short* Bb = B + (long)bx*256*K;
  const unsigned short* gA0 = Ab + (long)gr0*K + gc0;
  const unsigned short* gA1 = Ab + (long)gr1*K + gc1;
  const unsigned short* gB0 = Bb + (long)gr0*K + gc0;
  const unsigned short* gB1 = Bb + (long)gr1*K + gc1;

  // fragment read offsets (swizzled): slot = (fr>>1)&3
  const int wid = t>>6, lane = t&63;
  const int wm = wid>>2, wn = wid&3;
  const int fr = lane&15, fc = lane>>4;
  const int cb = (fc<<4) ^ (((fr>>1)&3)<<4);
  const int offA = (wm*128 + fr)*64 + cb;            // + i*1024
  const int offB = 16384 + (wn*64 + fr)*64 + cb;     // + j*1024

  fvec4 acc[8][4];
  #pragma unroll
  for (int i=0;i<8;i++){
    #pragma unroll
    for (int j=0;j<4;j++) acc[i][j] = (fvec4)(0.f);
  }

  const int NKT = K >> 5;
  auto stage = [&](int slot, int k0){
    char* sb = ldsc + slot*32768;
    async16(gA0 + k0, sb + t*16);
    async16(gA1 + k0, sb + 8192 + t*16);
    async16(gB0 + k0, sb + 16384 + t*16);
    async16(gB1 + k0, sb + 24576 + t*16);
  };

  stage(0, 0);   // prologue: tile 0 into slot 0

  for (int kt = 0; kt < NKT; ++kt){
    asm volatile("s_waitcnt vmcnt(0)" ::: "memory");  // my loads for tile kt done
    __builtin_amdgcn_s_barrier();                     // kt staged by all; other slot's readers done
    __builtin_amdgcn_sched_barrier(0);                // nothing below moves above the barrier
    if (kt+1 < NKT) stage((kt+1)&1, (kt+1)*32);       // prefetch next tile
    const char* sb = ldsc + (kt&1)*32768;
    bf16x8 af[8], bv[4];
    #pragma unroll
    for (int j=0;j<4;j++) bv[j] = *(const bf16x8*)(sb + offB + j*1024);
    #pragma unroll
    for (int i=0;i<8;i++) af[i] = *(const bf16x8*)(sb + offA + i*1024);
    __builtin_amdgcn_s_setprio(1);
    #pragma unroll
    for (int i=0;i<8;i++){
      #pragma unroll
      for (int j=0;j<4;j++){
        acc[i][j] = __builtin_amdgcn_mfma_f32_16x16x32_bf16(af[i], bv[j], acc[i][j], 0,0,0);
      }
    }
    __builtin_amdgcn_s_setprio(0);
  }

  const long crow0 = (long)by*256 + wm*128;
  const int  ccol0 = bx*256 + wn*64;
  #pragma unroll
  for (int i=0;i<8;i++){
    #pragma unroll
    for (int j=0;j<4;j++){
      #pragma unroll
      for (int q=0;q<4;q++){
        long rg = crow0 + i*16 + fc*4 + q;
        int  cg = ccol0 + j*16 + fr;
        float v = acc[i][j][q];
        if (MODE==0){
          if (cg < DINNER) Cb1[rg*DINNER + cg] = f2bf(v);
          else             Cb2[rg*DINNER + (cg-DINNER)] = f2bf(v);
        } else {
          Cf[rg*(long)ldc + cg] = v;
        }
      }
    }
  }
}

// ---------------- m97-style 128x128 GEMM for the small projections ----------------
// MODE 1: fp32 store, guard col<Nreal (x_proj)
// MODE 2: softplus(v+bias) -> bf16 (dt_proj -> delta)
template<int MODE>
__global__ __launch_bounds__(256) void gemm_bt(
    const unsigned short* __restrict__ A,
    const unsigned short* __restrict__ B,
    int K, int Nreal,
    float* __restrict__ Cf,
    unsigned short* __restrict__ Cb1,
    const float* __restrict__ bias,
    int ldc)
{
  __shared__ __align__(16) unsigned short As[128*32];
  __shared__ __align__(16) unsigned short Bs[128*32];
  const int t = threadIdx.x;
  const int bx = blockIdx.x, by = blockIdx.y;
  const int wave = t>>6, lane = t&63;
  const int wr = (wave>>1)*64, wc = (wave&1)*64;
  const int fr = lane&15, fc = lane>>4;
  fvec4 acc[4][4];
  #pragma unroll
  for(int i=0;i<4;i++){
    #pragma unroll
    for(int j=0;j<4;j++){ acc[i][j] = (fvec4)(0.f); }
  }
  const int srow = t>>2;
  const int scol = (t&3)*8;
  long rowA = (long)by*128 + srow;
  int rB0 = bx*128 + srow;      if (rB0 > Nreal-1) rB0 = Nreal-1;
  int rB1 = bx*128 + 64 + srow; if (rB1 > Nreal-1) rB1 = Nreal-1;
  const unsigned short* gA0 = A + rowA*(long)K + scol;
  const unsigned short* gA1 = gA0 + 64L*K;
  const unsigned short* gB0 = B + (long)rB0*K + scol;
  const unsigned short* gB1 = B + (long)rB1*K + scol;
  unsigned short* lA0 = &As[t*8];
  unsigned short* lA1 = &As[2048 + t*8];
  unsigned short* lB0 = &Bs[t*8];
  unsigned short* lB1 = &Bs[2048 + t*8];

  for (int k0 = 0; k0 < K; k0 += 32){
    async16(gA0 + k0, lA0);
    async16(gA1 + k0, lA1);
    async16(gB0 + k0, lB0);
    async16(gB1 + k0, lB1);
    __syncthreads();
    bf16x8 af[4], bv[4];
    #pragma unroll
    for(int i=0;i<4;i++){
      af[i] = *(const bf16x8*)&As[(wr + i*16 + fr)*32 + fc*8];
      bv[i] = *(const bf16x8*)&Bs[(wc + i*16 + fr)*32 + fc*8];
    }
    #pragma unroll
    for(int i=0;i<4;i++){
      #pragma unroll
      for(int j=0;j<4;j++){
        acc[i][j] = __builtin_amdgcn_mfma_f32_16x16x32_bf16(af[i], bv[j], acc[i][j], 0,0,0);
      }
    }
    __syncthreads();
  }

  const long crow0 = (long)by*128 + wr;
  const int ccol0 = bx*128 + wc;
  #pragma unroll
  for(int i=0;i<4;i++){
    #pragma unroll
    for(int j=0;j<4;j++){
      #pragma unroll
      for(int q=0;q<4;q++){
        long rg = crow0 + i*16 + fc*4 + q;
        int  cg = ccol0 + j*16 + fr;
        float v = acc[i][j][q];
        if (MODE==1){
          if (cg < Nreal) Cf[rg*ldc + cg] = v;
        } else if (MODE==2){
          float x = v + bias[cg];
          float sp = (x > 20.f) ? x : log1pf(__expf(x));
          Cb1[rg*ldc + cg] = f2bf(sp);
        }
      }
    }
  }
}

// ---------------- depthwise causal conv(4) + bias + SiLU ----------------
__global__ __launch_bounds__(256) void conv_silu_kernel(
    const unsigned short* __restrict__ xb, const float* __restrict__ w,
    const float* __restrict__ bias, unsigned short* __restrict__ ub)
{
  int gid = blockIdx.x*256 + threadIdx.x;
  int d0 = (gid & 511)*8;
  long m = gid >> 9;
  int l = (int)(m & (SEQ-1));
  fvec4 w4[8];
  #pragma unroll
  for(int k=0;k<8;k++) w4[k] = *(const fvec4*)&w[(d0+k)*4];
  float acc[8];
  fvec4 b0 = *(const fvec4*)&bias[d0];
  fvec4 b1 = *(const fvec4*)&bias[d0+4];
  acc[0]=b0[0];acc[1]=b0[1];acc[2]=b0[2];acc[3]=b0[3];
  acc[4]=b1[0];acc[5]=b1[1];acc[6]=b1[2];acc[7]=b1[3];
  #pragma unroll
  for(int j=0;j<4;j++){
    int lj = l-3+j;
    if (lj >= 0){
      ivec4 xv = *(const ivec4*)&xb[(m-3+j)*DINNER + d0];
      float xs[8];
      #pragma unroll
      for(int q=0;q<4;q++){
        unsigned int wd = (unsigned int)xv[q];
        xs[2*q]   = bf2f((unsigned short)(wd & 0xffffu));
        xs[2*q+1] = bf2f((unsigned short)(wd >> 16));
      }
      #pragma unroll
      for(int k=0;k<8;k++) acc[k] += xs[k]*w4[k][j];
    }
  }
  ivec4 ov;
  #pragma unroll
  for(int q=0;q<4;q++){
    float y0 = acc[2*q]  * sigf(acc[2*q]);
    float y1 = acc[2*q+1]* sigf(acc[2*q+1]);
    ov[q] = (int)((unsigned)f2bf(y0) | ((unsigned)f2bf(y1) << 16));
  }
  *(ivec4*)&ub[m*DINNER + d0] = ov;
}

// ---------------- new_conv_state ----------------
__global__ void conv_state_kernel(const unsigned short* __restrict__ xb, float* __restrict__ out){
  int i = blockIdx.x*256 + threadIdx.x;
  int b = i >> 14; int r = i & 16383; int dd = r >> 2; int j = r & 3;
  out[i] = bf2f(xb[((long)(b*SEQ + (SEQ-4) + j))*DINNER + dd]);
}

// ---------------- xdbl[:, :128] -> bf16 for dt_proj A ----------------
__global__ void cvt_dtr_kernel(const float* __restrict__ xdbl, unsigned short* __restrict__ dtr){
  int i = blockIdx.x*256 + threadIdx.x;
  long mrow = i >> 5; int c = (i & 31)*4;
  fvec4 v = *(const fvec4*)&xdbl[mrow*160 + c];
  usvec4 o; o[0]=f2bf(v[0]); o[1]=f2bf(v[1]); o[2]=f2bf(v[2]); o[3]=f2bf(v[3]);
  *(usvec4*)&dtr[mrow*DTRANK + c] = o;
}

// ================= chunked parallel scan =================
__global__ __launch_bounds__(256) void scan_part1(
    const unsigned short* __restrict__ delta_b,
    const unsigned short* __restrict__ u_b,
    const float* __restrict__ xdbl,
    const float* __restrict__ Amat,
    float* __restrict__ S,
    float* __restrict__ sdelta)
{
  const int t = threadIdx.x;
  const int blk = blockIdx.x;
  const int c = blk & 15, b = (blk>>4)&3, d = (blk>>6)*256 + t;
  float a[16], s[16];
  #pragma unroll
  for (int n=0;n<16;n++){ a[n] = Amat[n*DINNER+d]; s[n]=0.f; }
  float sd = 0.f;
  const long mbase = (long)b*SEQ + c*LC;
  for (int l=0;l<LC;l++){
    long m = mbase + l;
    float dl = bf2f(delta_b[m*DINNER+d]);
    float ul = bf2f(u_b[m*DINNER+d]);
    const float* xb = &xdbl[m*160 + 128];
    float dbu = dl*ul;
    sd += dl;
    #pragma unroll
    for (int g=0; g<4; g++){
      fvec4 Bg = *(const fvec4*)(xb + 4*g);
      #pragma unroll
      for (int q=0;q<4;q++){
        int n = g*4+q;
        s[n] = __expf(dl*a[n])*s[n] + Bg[q]*dbu;
      }
    }
  }
  const long base = ((long)(b*NCHUNK + c)*DSTATE)*DINNER + d;
  #pragma unroll
  for (int n=0;n<16;n++) S[base + (long)n*DINNER] = s[n];
  sdelta[(long)(b*NCHUNK+c)*DINNER + d] = sd;
}

__global__ __launch_bounds__(256) void scan_part2(
    const float* __restrict__ S,
    const float* __restrict__ sdelta,
    const float* __restrict__ Amat,
    float* __restrict__ Xin,
    float* __restrict__ last_state)
{
  int id = blockIdx.x*256 + threadIdx.x;
  int d = id & (DINNER-1);
  int n = (id>>12) & 15;
  int b = id>>16;
  float a = Amat[n*DINNER+d];
  float X = 0.f;
  #pragma unroll
  for (int c=0;c<NCHUNK;c++){
    long sb = ((long)(b*NCHUNK+c)*DSTATE + n)*DINNER + d;
    Xin[sb] = X;
    float sd = sdelta[(long)(b*NCHUNK+c)*DINNER + d];
    float Sc = S[sb];
    X = __expf(a*sd)*X + Sc;
  }
  last_state[((long)b*DSTATE + n)*DINNER + d] = X;
}

__global__ __launch_bounds__(256) void scan_part3(
    const unsigned short* __restrict__ delta_b,
    const unsigned short* __restrict__ u_b,
    const unsigned short* __restrict__ z_b,
    const float* __restrict__ xdbl,
    const float* __restrict__ Amat,
    const float* __restrict__ Dvec,
    const float* __restrict__ Xin,
    unsigned short* __restrict__ y_b)
{
  const int t = threadIdx.x;
  const int blk = blockIdx.x;
  const int c = blk & 15, b = (blk>>4)&3, d = (blk>>6)*256 + t;
  float a[16], s[16];
  const long xb0 = ((long)(b*NCHUNK + c)*DSTATE)*DINNER + d;
  #pragma unroll
  for (int n=0;n<16;n++){
    a[n] = Amat[n*DINNER+d];
    s[n] = Xin[xb0 + (long)n*DINNER];
  }
  const float Dd = Dvec[d];
  const long mbase = (long)b*SEQ + c*LC;
  for (int l=0;l<LC;l++){
    long m = mbase + l;
    float dl = bf2f(delta_b[m*DINNER+d]);
    float ul = bf2f(u_b[m*DINNER+d]);
    float zl = bf2f(z_b[m*DINNER+d]);
    const float* xb = &xdbl[m*160 + 128];
    float dbu = dl*ul;
    float y = 0.f;
    #pragma unroll
    for (int g=0; g<4; g++){
      fvec4 Bg = *(const fvec4*)(xb + 4*g);
      fvec4 Cg = *(const fvec4*)(xb + 16 + 4*g);
      #pragma unroll
      for (int q=0;q<4;q++){
        int n = g*4+q;
        s[n] = __expf(dl*a[n])*s[n] + Bg[q]*dbu;
        y += Cg[q]*s[n];
      }
    }
    float yy = y + ul*Dd;
    float zs = zl*sigf(zl);
    y_b[m*DINNER+d] = f2bf(yy*zs);
  }
}

// ---------------- launcher ----------------
// Aliased 256 MiB layout:
//   Slot A [0,64M):    hs_b(32M)+w_in_b(32M) -> delta(64M) after in_proj
//   Slot B [64,128M):  x(64M) -> after conv: wxp@64 wdt@66 wout@68 xdbl@84
//                      dtr@90 S@92(16M) Xin@108(16M) sdelta@124(1M)
//   Slot C [128,192M): z(64M)
//   Slot D [192,256M): u(64M) -> y written in-place by scan_part3
extern "C" void kernel_launch(void* const* d_in, const int* in_sizes, int n_in,
                              void* d_out, int out_size, void* d_ws, size_t ws_size,
                              hipStream_t stream) {
  const float* hs     = (const float*)d_in[0];
  const float* w_in   = (const float*)d_in[6];
  const float* conv_w = (const float*)d_in[7];
  const float* conv_b = (const float*)d_in[8];
  const float* w_xp   = (const float*)d_in[9];
  const float* w_dt   = (const float*)d_in[10];
  const float* dt_bias= (const float*)d_in[11];
  const float* Amat   = (const float*)d_in[12];
  const float* Dvec   = (const float*)d_in[13];
  const float* w_out  = (const float*)d_in[14];
  float* out = (float*)d_out;

  char* ws = (char*)d_ws;
  const size_t MiB = (size_t)1 << 20;

  unsigned short *hs_b, *w_in_b, *x_b, *z_b, *u_b, *delta_b;
  unsigned short *wxp_b, *wdt_b, *wout_b, *dtr_b, *y_b;
  float *xdbl, *Sbuf, *Xin, *sdelta;

  if (ws_size >= 400*MiB){
    size_t off = 0;
    auto alloc = [&](size_t bytes)->void*{ void* p = ws + off; off += (bytes + 255) & ~(size_t)255; return p; };
    hs_b   = (unsigned short*)alloc((size_t)MROWS*DMODEL*2);
    w_in_b = (unsigned short*)alloc((size_t)2*DINNER*DMODEL*2);
    x_b    = (unsigned short*)alloc((size_t)MROWS*DINNER*2);
    z_b    = (unsigned short*)alloc((size_t)MROWS*DINNER*2);
    u_b    = (unsigned short*)alloc((size_t)MROWS*DINNER*2);
    delta_b= (unsigned short*)alloc((size_t)MROWS*DINNER*2);
    wxp_b  = (unsigned short*)alloc((size_t)160*DINNER*2);
    wdt_b  = (unsigned short*)alloc((size_t)DINNER*DTRANK*2);
    wout_b = (unsigned short*)alloc((size_t)DMODEL*DINNER*2);
    xdbl   = (float*)alloc((size_t)MROWS*160*4);
    dtr_b  = (unsigned short*)alloc((size_t)MROWS*DTRANK*2);
    Sbuf   = (float*)alloc((size_t)NB*NCHUNK*DSTATE*DINNER*4);
    Xin    = (float*)alloc((size_t)NB*NCHUNK*DSTATE*DINNER*4);
    sdelta = (float*)alloc((size_t)NB*NCHUNK*DINNER*4);
    y_b    = x_b;
  } else {
    hs_b    = (unsigned short*)(ws + 0);
    w_in_b  = (unsigned short*)(ws + 32*MiB);
    delta_b = (unsigned short*)(ws + 0);
    x_b     = (unsigned short*)(ws + 64*MiB);
    wxp_b   = (unsigned short*)(ws + 64*MiB);
    wdt_b   = (unsigned short*)(ws + 66*MiB);
    wout_b  = (unsigned short*)(ws + 68*MiB);
    xdbl    = (float*)         (ws + 84*MiB);
    dtr_b   = (unsigned short*)(ws + 90*MiB);
    Sbuf    = (float*)         (ws + 92*MiB);
    Xin     = (float*)         (ws + 108*MiB);
    sdelta  = (float*)         (ws + 124*MiB);
    z_b     = (unsigned short*)(ws + 128*MiB);
    u_b     = (unsigned short*)(ws + 192*MiB);
    y_b     = u_b;
  }

  // 1) converts needed for in_proj
  cvt_bf16_kernel<<<(MROWS*DMODEL)/1024, 256, 0, stream>>>(hs, hs_b, MROWS*DMODEL);
  cvt_bf16_kernel<<<(2*DINNER*DMODEL)/1024, 256, 0, stream>>>(w_in, w_in_b, 2*DINNER*DMODEL);

  // 2) in_proj: (8192x2048)@(8192x2048)^T, 256^2 tiles -> 32x32=1024 blocks
  gemm256<0><<<1024, 512, 0, stream>>>(hs_b, w_in_b, DMODEL, 32, 0,
                                       x_b, z_b, nullptr);
  // 3) new_conv_state
  conv_state_kernel<<<256, 256, 0, stream>>>(x_b, out + (size_t)MROWS*DMODEL);
  // 4) conv + silu -> u (x dead afterwards)
  conv_silu_kernel<<<(MROWS*512)/256, 256, 0, stream>>>(x_b, conv_w, conv_b, u_b);

  // 5) weight converts (into dead-x slot in aliased mode)
  cvt_bf16_kernel<<<(160*DINNER)/1024, 256, 0, stream>>>(w_xp, wxp_b, 160*DINNER);
  cvt_bf16_kernel<<<(DINNER*DTRANK)/1024, 256, 0, stream>>>(w_dt, wdt_b, DINNER*DTRANK);
  cvt_bf16_kernel<<<(DMODEL*DINNER)/1024, 256, 0, stream>>>(w_out, wout_b, DMODEL*DINNER);

  // 6) x_proj -> xdbl fp32
  gemm_bt<1><<<dim3(2,64), 256, 0, stream>>>(u_b, wxp_b, DINNER, 160,
                                             xdbl, nullptr, nullptr, 160);
  // 7) dtr bf16
  cvt_dtr_kernel<<<(MROWS*32)/256, 256, 0, stream>>>(xdbl, dtr_b);
  // 8) dt_proj + softplus -> delta
  gemm_bt<2><<<dim3(32,64), 256, 0, stream>>>(dtr_b, wdt_b, DTRANK, DINNER,
                                              nullptr, delta_b, dt_bias, DINNER);
  // 9) chunked scan
  scan_part1<<<1024, 256, 0, stream>>>(delta_b, u_b, xdbl, Amat, Sbuf, sdelta);
  scan_part2<<<1024, 256, 0, stream>>>(Sbuf, sdelta, Amat, Xin,
                                       out + (size_t)MROWS*DMODEL + NB*DINNER*4);
  scan_part3<<<1024, 256, 0, stream>>>(delta_b, u_b, z_b, xdbl, Amat, Dvec, Xin, y_b);
  // 10) out_proj: (8192x4096)@(2048x4096)^T, 32x8=256 blocks
  gemm256<3><<<256, 512, 0, stream>>>(y_b, wout_b, DINNER, 8, DMODEL,
                                      nullptr, nullptr, out);
}

// Round 6
// 1010.778 us; speedup vs baseline: 4.5927x; 4.5927x over previous
//
#include <hip/hip_runtime.h>
#include <hip/hip_bf16.h>
#include <math.h>

typedef __attribute__((ext_vector_type(4))) float fvec4;
typedef __attribute__((ext_vector_type(2))) float fvec2;
typedef __attribute__((ext_vector_type(4))) int ivec4;
typedef __attribute__((ext_vector_type(4))) unsigned short usvec4;
typedef __attribute__((ext_vector_type(8))) short bf16x8;

#define SEQ 2048
#define DMODEL 2048
#define DINNER 4096
#define DSTATE 16
#define DTRANK 128
#define NB 4
#define MROWS (NB*SEQ)  // 8192
#define NCHUNK 16
#define LC (SEQ/NCHUNK) // 128

__device__ __forceinline__ float bf2f(unsigned short h){
  union{unsigned int u; float f;} v; v.u = ((unsigned int)h)<<16; return v.f;
}
__device__ __forceinline__ unsigned short f2bf(float f){
  union{float f; unsigned int u;} v; v.f=f;
  unsigned int r = v.u + 0x7fffu + ((v.u>>16)&1u);
  return (unsigned short)(r>>16);
}
__device__ __forceinline__ void async16(const void* g, void* l){
  __builtin_amdgcn_global_load_lds((const __attribute__((address_space(1))) void*)g,
                                   (__attribute__((address_space(3))) void*)l, 16, 0, 0);
}
__device__ __forceinline__ float sigf(float x){ return 1.f/(1.f+__expf(-x)); }

// ---------------- fp32 -> bf16 convert ----------------
__global__ void cvt_bf16_kernel(const float* __restrict__ in, unsigned short* __restrict__ out, int n){
  int i = (blockIdx.x*256 + threadIdx.x)*4;
  if (i >= n) return;
  fvec4 v = *(const fvec4*)(in + i);
  usvec4 o;
  o[0]=f2bf(v[0]); o[1]=f2bf(v[1]); o[2]=f2bf(v[2]); o[3]=f2bf(v[3]);
  *(usvec4*)(out + i) = o;
}

// ================= 256x256 GEMM (C = A * B^T), 2-slot ring =================
// BK=32, 2-slot LDS ring (64 KiB), ONE barrier per K-step:
//   [vmcnt(0): my 4 loads for tile kt done] -> [s_barrier: everyone staged kt,
//   everyone's reads of the other slot done] -> [stage kt+1 into other slot]
//   -> [read slot kt, MFMA].
// Race-free: a wave passes barrier kt only after its iter-(kt-1) MFMAs (and
// hence ds_reads) retired; staging into the other slot happens after that
// barrier. Stage->wait distance = one full compute phase (~1240cy > HBM 900).
// T2 swizzle (verified 0 conflicts in r5): slot s=(row>>1)&3, involution
// pre-applied to the global source. T1 XCD swizzle.
// __launch_bounds__(512,2): 2 waves/SIMD -> 256-reg budget. (512,4) spilled
// the 128-reg accumulator to scratch (r5: 9x regression) — do not raise.
// MODE 0: split x/z bf16 at col 4096 (in_proj). MODE 3: fp32 store (out_proj).
template<int MODE>
__global__ __launch_bounds__(512, 2) void gemm256(
    const unsigned short* __restrict__ A,
    const unsigned short* __restrict__ B,
    int K, int nbx, int ldc,
    unsigned short* __restrict__ Cb1,
    unsigned short* __restrict__ Cb2,
    float* __restrict__ Cf)
{
  __shared__ __align__(16) unsigned short lds[32768];  // 2 slots x 32 KiB
  char* ldsc = (char*)lds;
  const int t = threadIdx.x;

  // T1: XCD swizzle (gridDim.x % 8 == 0 for all uses)
  const int nwg = gridDim.x;
  const int cpx = nwg >> 3;
  const int bid = blockIdx.x;
  const int swzb = (bid & 7)*cpx + (bid >> 3);
  const int bx = swzb % nbx, by = swzb / nbx;

  // staging source: pre-apply the LDS swizzle involution to the global source
  // byte ^= ((byte>>7)&3)<<4  (within each operand's 16 KiB region)
  const int bA0 = t*16, bA1 = 8192 + t*16;
  const int sw0 = bA0 ^ (((bA0>>7)&3)<<4);
  const int sw1 = bA1 ^ (((bA1>>7)&3)<<4);
  const int gr0 = sw0>>6, gc0 = (sw0&63)>>1;
  const int gr1 = sw1>>6, gc1 = (sw1&63)>>1;
  const unsigned short* Ab = A + (long)by*256*K;
  const unsigned short* Bb = B + (long)bx*256*K;
  const unsigned short* gA0 = Ab + (long)gr0*K + gc0;
  const unsigned short* gA1 = Ab + (long)gr1*K + gc1;
  const unsigned short* gB0 = Bb + (long)gr0*K + gc0;
  const unsigned short* gB1 = Bb + (long)gr1*K + gc1;

  // fragment read offsets (swizzled): slot = (fr>>1)&3
  const int wid = t>>6, lane = t&63;
  const int wm = wid>>2, wn = wid&3;
  const int fr = lane&15, fc = lane>>4;
  const int cb = (fc<<4) ^ (((fr>>1)&3)<<4);
  const int offA = (wm*128 + fr)*64 + cb;            // + i*1024
  const int offB = 16384 + (wn*64 + fr)*64 + cb;     // + j*1024

  fvec4 acc[8][4];
  #pragma unroll
  for (int i=0;i<8;i++){
    #pragma unroll
    for (int j=0;j<4;j++) acc[i][j] = (fvec4)(0.f);
  }

  const int NKT = K >> 5;
  auto stage = [&](int slot, int k0){
    char* sb = ldsc + slot*32768;
    async16(gA0 + k0, sb + t*16);
    async16(gA1 + k0, sb + 8192 + t*16);
    async16(gB0 + k0, sb + 16384 + t*16);
    async16(gB1 + k0, sb + 24576 + t*16);
  };

  stage(0, 0);   // prologue: tile 0 into slot 0

  for (int kt = 0; kt < NKT; ++kt){
    asm volatile("s_waitcnt vmcnt(0)" ::: "memory");  // my loads for tile kt done
    __builtin_amdgcn_s_barrier();                     // kt staged by all; other slot's readers done
    __builtin_amdgcn_sched_barrier(0);                // nothing below moves above the barrier
    if (kt+1 < NKT) stage((kt+1)&1, (kt+1)*32);       // prefetch next tile
    const char* sb = ldsc + (kt&1)*32768;
    bf16x8 af[8], bv[4];
    #pragma unroll
    for (int j=0;j<4;j++) bv[j] = *(const bf16x8*)(sb + offB + j*1024);
    #pragma unroll
    for (int i=0;i<8;i++) af[i] = *(const bf16x8*)(sb + offA + i*1024);
    __builtin_amdgcn_s_setprio(1);
    #pragma unroll
    for (int i=0;i<8;i++){
      #pragma unroll
      for (int j=0;j<4;j++){
        acc[i][j] = __builtin_amdgcn_mfma_f32_16x16x32_bf16(af[i], bv[j], acc[i][j], 0,0,0);
      }
    }
    __builtin_amdgcn_s_setprio(0);
  }

  const long crow0 = (long)by*256 + wm*128;
  const int  ccol0 = bx*256 + wn*64;
  #pragma unroll
  for (int i=0;i<8;i++){
    #pragma unroll
    for (int j=0;j<4;j++){
      #pragma unroll
      for (int q=0;q<4;q++){
        long rg = crow0 + i*16 + fc*4 + q;
        int  cg = ccol0 + j*16 + fr;
        float v = acc[i][j][q];
        if (MODE==0){
          if (cg < DINNER) Cb1[rg*DINNER + cg] = f2bf(v);
          else             Cb2[rg*DINNER + (cg-DINNER)] = f2bf(v);
        } else {
          Cf[rg*(long)ldc + cg] = v;
        }
      }
    }
  }
}

// ---------------- m97-style 128x128 GEMM for the small projections ----------------
// MODE 1: fp32 store, guard col<Nreal (x_proj)
// MODE 2: softplus(v+bias) -> bf16 (dt_proj -> delta)
template<int MODE>
__global__ __launch_bounds__(256) void gemm_bt(
    const unsigned short* __restrict__ A,
    const unsigned short* __restrict__ B,
    int K, int Nreal,
    float* __restrict__ Cf,
    unsigned short* __restrict__ Cb1,
    const float* __restrict__ bias,
    int ldc)
{
  __shared__ __align__(16) unsigned short As[128*32];
  __shared__ __align__(16) unsigned short Bs[128*32];
  const int t = threadIdx.x;
  const int bx = blockIdx.x, by = blockIdx.y;
  const int wave = t>>6, lane = t&63;
  const int wr = (wave>>1)*64, wc = (wave&1)*64;
  const int fr = lane&15, fc = lane>>4;
  fvec4 acc[4][4];
  #pragma unroll
  for(int i=0;i<4;i++){
    #pragma unroll
    for(int j=0;j<4;j++){ acc[i][j] = (fvec4)(0.f); }
  }
  const int srow = t>>2;
  const int scol = (t&3)*8;
  long rowA = (long)by*128 + srow;
  int rB0 = bx*128 + srow;      if (rB0 > Nreal-1) rB0 = Nreal-1;
  int rB1 = bx*128 + 64 + srow; if (rB1 > Nreal-1) rB1 = Nreal-1;
  const unsigned short* gA0 = A + rowA*(long)K + scol;
  const unsigned short* gA1 = gA0 + 64L*K;
  const unsigned short* gB0 = B + (long)rB0*K + scol;
  const unsigned short* gB1 = B + (long)rB1*K + scol;
  unsigned short* lA0 = &As[t*8];
  unsigned short* lA1 = &As[2048 + t*8];
  unsigned short* lB0 = &Bs[t*8];
  unsigned short* lB1 = &Bs[2048 + t*8];

  for (int k0 = 0; k0 < K; k0 += 32){
    async16(gA0 + k0, lA0);
    async16(gA1 + k0, lA1);
    async16(gB0 + k0, lB0);
    async16(gB1 + k0, lB1);
    __syncthreads();
    bf16x8 af[4], bv[4];
    #pragma unroll
    for(int i=0;i<4;i++){
      af[i] = *(const bf16x8*)&As[(wr + i*16 + fr)*32 + fc*8];
      bv[i] = *(const bf16x8*)&Bs[(wc + i*16 + fr)*32 + fc*8];
    }
    #pragma unroll
    for(int i=0;i<4;i++){
      #pragma unroll
      for(int j=0;j<4;j++){
        acc[i][j] = __builtin_amdgcn_mfma_f32_16x16x32_bf16(af[i], bv[j], acc[i][j], 0,0,0);
      }
    }
    __syncthreads();
  }

  const long crow0 = (long)by*128 + wr;
  const int ccol0 = bx*128 + wc;
  #pragma unroll
  for(int i=0;i<4;i++){
    #pragma unroll
    for(int j=0;j<4;j++){
      #pragma unroll
      for(int q=0;q<4;q++){
        long rg = crow0 + i*16 + fc*4 + q;
        int  cg = ccol0 + j*16 + fr;
        float v = acc[i][j][q];
        if (MODE==1){
          if (cg < Nreal) Cf[rg*ldc + cg] = v;
        } else if (MODE==2){
          float x = v + bias[cg];
          float sp = (x > 20.f) ? x : log1pf(__expf(x));
          Cb1[rg*ldc + cg] = f2bf(sp);
        }
      }
    }
  }
}

// ---------------- depthwise causal conv(4) + bias + SiLU ----------------
__global__ __launch_bounds__(256) void conv_silu_kernel(
    const unsigned short* __restrict__ xb, const float* __restrict__ w,
    const float* __restrict__ bias, unsigned short* __restrict__ ub)
{
  int gid = blockIdx.x*256 + threadIdx.x;
  int d0 = (gid & 511)*8;
  long m = gid >> 9;
  int l = (int)(m & (SEQ-1));
  fvec4 w4[8];
  #pragma unroll
  for(int k=0;k<8;k++) w4[k] = *(const fvec4*)&w[(d0+k)*4];
  float acc[8];
  fvec4 b0 = *(const fvec4*)&bias[d0];
  fvec4 b1 = *(const fvec4*)&bias[d0+4];
  acc[0]=b0[0];acc[1]=b0[1];acc[2]=b0[2];acc[3]=b0[3];
  acc[4]=b1[0];acc[5]=b1[1];acc[6]=b1[2];acc[7]=b1[3];
  #pragma unroll
  for(int j=0;j<4;j++){
    int lj = l-3+j;
    if (lj >= 0){
      ivec4 xv = *(const ivec4*)&xb[(m-3+j)*DINNER + d0];
      float xs[8];
      #pragma unroll
      for(int q=0;q<4;q++){
        unsigned int wd = (unsigned int)xv[q];
        xs[2*q]   = bf2f((unsigned short)(wd & 0xffffu));
        xs[2*q+1] = bf2f((unsigned short)(wd >> 16));
      }
      #pragma unroll
      for(int k=0;k<8;k++) acc[k] += xs[k]*w4[k][j];
    }
  }
  ivec4 ov;
  #pragma unroll
  for(int q=0;q<4;q++){
    float y0 = acc[2*q]  * sigf(acc[2*q]);
    float y1 = acc[2*q+1]* sigf(acc[2*q+1]);
    ov[q] = (int)((unsigned)f2bf(y0) | ((unsigned)f2bf(y1) << 16));
  }
  *(ivec4*)&ub[m*DINNER + d0] = ov;
}

// ---------------- new_conv_state ----------------
__global__ void conv_state_kernel(const unsigned short* __restrict__ xb, float* __restrict__ out){
  int i = blockIdx.x*256 + threadIdx.x;
  int b = i >> 14; int r = i & 16383; int dd = r >> 2; int j = r & 3;
  out[i] = bf2f(xb[((long)(b*SEQ + (SEQ-4) + j))*DINNER + dd]);
}

// ---------------- xdbl[:, :128] -> bf16 for dt_proj A ----------------
__global__ void cvt_dtr_kernel(const float* __restrict__ xdbl, unsigned short* __restrict__ dtr){
  int i = blockIdx.x*256 + threadIdx.x;
  long mrow = i >> 5; int c = (i & 31)*4;
  fvec4 v = *(const fvec4*)&xdbl[mrow*160 + c];
  usvec4 o; o[0]=f2bf(v[0]); o[1]=f2bf(v[1]); o[2]=f2bf(v[2]); o[3]=f2bf(v[3]);
  *(usvec4*)&dtr[mrow*DTRANK + c] = o;
}

// ================= chunked parallel scan =================
__global__ __launch_bounds__(256) void scan_part1(
    const unsigned short* __restrict__ delta_b,
    const unsigned short* __restrict__ u_b,
    const float* __restrict__ xdbl,
    const float* __restrict__ Amat,
    float* __restrict__ S,
    float* __restrict__ sdelta)
{
  const int t = threadIdx.x;
  const int blk = blockIdx.x;
  const int c = blk & 15, b = (blk>>4)&3, d = (blk>>6)*256 + t;
  float a[16], s[16];
  #pragma unroll
  for (int n=0;n<16;n++){ a[n] = Amat[n*DINNER+d]; s[n]=0.f; }
  float sd = 0.f;
  const long mbase = (long)b*SEQ + c*LC;
  for (int l=0;l<LC;l++){
    long m = mbase + l;
    float dl = bf2f(delta_b[m*DINNER+d]);
    float ul = bf2f(u_b[m*DINNER+d]);
    const float* xb = &xdbl[m*160 + 128];
    float dbu = dl*ul;
    sd += dl;
    #pragma unroll
    for (int g=0; g<4; g++){
      fvec4 Bg = *(const fvec4*)(xb + 4*g);
      #pragma unroll
      for (int q=0;q<4;q++){
        int n = g*4+q;
        s[n] = __expf(dl*a[n])*s[n] + Bg[q]*dbu;
      }
    }
  }
  const long base = ((long)(b*NCHUNK + c)*DSTATE)*DINNER + d;
  #pragma unroll
  for (int n=0;n<16;n++) S[base + (long)n*DINNER] = s[n];
  sdelta[(long)(b*NCHUNK+c)*DINNER + d] = sd;
}

__global__ __launch_bounds__(256) void scan_part2(
    const float* __restrict__ S,
    const float* __restrict__ sdelta,
    const float* __restrict__ Amat,
    float* __restrict__ Xin,
    float* __restrict__ last_state)
{
  int id = blockIdx.x*256 + threadIdx.x;
  int d = id & (DINNER-1);
  int n = (id>>12) & 15;
  int b = id>>16;
  float a = Amat[n*DINNER+d];
  float X = 0.f;
  #pragma unroll
  for (int c=0;c<NCHUNK;c++){
    long sb = ((long)(b*NCHUNK+c)*DSTATE + n)*DINNER + d;
    Xin[sb] = X;
    float sd = sdelta[(long)(b*NCHUNK+c)*DINNER + d];
    float Sc = S[sb];
    X = __expf(a*sd)*X + Sc;
  }
  last_state[((long)b*DSTATE + n)*DINNER + d] = X;
}

__global__ __launch_bounds__(256) void scan_part3(
    const unsigned short* __restrict__ delta_b,
    const unsigned short* __restrict__ u_b,
    const unsigned short* __restrict__ z_b,
    const float* __restrict__ xdbl,
    const float* __restrict__ Amat,
    const float* __restrict__ Dvec,
    const float* __restrict__ Xin,
    unsigned short* __restrict__ y_b)
{
  const int t = threadIdx.x;
  const int blk = blockIdx.x;
  const int c = blk & 15, b = (blk>>4)&3, d = (blk>>6)*256 + t;
  float a[16], s[16];
  const long xb0 = ((long)(b*NCHUNK + c)*DSTATE)*DINNER + d;
  #pragma unroll
  for (int n=0;n<16;n++){
    a[n] = Amat[n*DINNER+d];
    s[n] = Xin[xb0 + (long)n*DINNER];
  }
  const float Dd = Dvec[d];
  const long mbase = (long)b*SEQ + c*LC;
  for (int l=0;l<LC;l++){
    long m = mbase + l;
    float dl = bf2f(delta_b[m*DINNER+d]);
    float ul = bf2f(u_b[m*DINNER+d]);
    float zl = bf2f(z_b[m*DINNER+d]);
    const float* xb = &xdbl[m*160 + 128];
    float dbu = dl*ul;
    float y = 0.f;
    #pragma unroll
    for (int g=0; g<4; g++){
      fvec4 Bg = *(const fvec4*)(xb + 4*g);
      fvec4 Cg = *(const fvec4*)(xb + 16 + 4*g);
      #pragma unroll
      for (int q=0;q<4;q++){
        int n = g*4+q;
        s[n] = __expf(dl*a[n])*s[n] + Bg[q]*dbu;
        y += Cg[q]*s[n];
      }
    }
    float yy = y + ul*Dd;
    float zs = zl*sigf(zl);
    y_b[m*DINNER+d] = f2bf(yy*zs);
  }
}

// ---------------- launcher ----------------
// Aliased 256 MiB layout:
//   Slot A [0,64M):    hs_b(32M)+w_in_b(32M) -> delta(64M) after in_proj
//   Slot B [64,128M):  x(64M) -> after conv: wxp@64 wdt@66 wout@68 xdbl@84
//                      dtr@90 S@92(16M) Xin@108(16M) sdelta@124(1M)
//   Slot C [128,192M): z(64M)
//   Slot D [192,256M): u(64M) -> y written in-place by scan_part3
extern "C" void kernel_launch(void* const* d_in, const int* in_sizes, int n_in,
                              void* d_out, int out_size, void* d_ws, size_t ws_size,
                              hipStream_t stream) {
  const float* hs     = (const float*)d_in[0];
  const float* w_in   = (const float*)d_in[6];
  const float* conv_w = (const float*)d_in[7];
  const float* conv_b = (const float*)d_in[8];
  const float* w_xp   = (const float*)d_in[9];
  const float* w_dt   = (const float*)d_in[10];
  const float* dt_bias= (const float*)d_in[11];
  const float* Amat   = (const float*)d_in[12];
  const float* Dvec   = (const float*)d_in[13];
  const float* w_out  = (const float*)d_in[14];
  float* out = (float*)d_out;

  char* ws = (char*)d_ws;
  const size_t MiB = (size_t)1 << 20;

  unsigned short *hs_b, *w_in_b, *x_b, *z_b, *u_b, *delta_b;
  unsigned short *wxp_b, *wdt_b, *wout_b, *dtr_b, *y_b;
  float *xdbl, *Sbuf, *Xin, *sdelta;

  if (ws_size >= 400*MiB){
    size_t off = 0;
    auto alloc = [&](size_t bytes)->void*{ void* p = ws + off; off += (bytes + 255) & ~(size_t)255; return p; };
    hs_b   = (unsigned short*)alloc((size_t)MROWS*DMODEL*2);
    w_in_b = (unsigned short*)alloc((size_t)2*DINNER*DMODEL*2);
    x_b    = (unsigned short*)alloc((size_t)MROWS*DINNER*2);
    z_b    = (unsigned short*)alloc((size_t)MROWS*DINNER*2);
    u_b    = (unsigned short*)alloc((size_t)MROWS*DINNER*2);
    delta_b= (unsigned short*)alloc((size_t)MROWS*DINNER*2);
    wxp_b  = (unsigned short*)alloc((size_t)160*DINNER*2);
    wdt_b  = (unsigned short*)alloc((size_t)DINNER*DTRANK*2);
    wout_b = (unsigned short*)alloc((size_t)DMODEL*DINNER*2);
    xdbl   = (float*)alloc((size_t)MROWS*160*4);
    dtr_b  = (unsigned short*)alloc((size_t)MROWS*DTRANK*2);
    Sbuf   = (float*)alloc((size_t)NB*NCHUNK*DSTATE*DINNER*4);
    Xin    = (float*)alloc((size_t)NB*NCHUNK*DSTATE*DINNER*4);
    sdelta = (float*)alloc((size_t)NB*NCHUNK*DINNER*4);
    y_b    = x_b;
  } else {
    hs_b    = (unsigned short*)(ws + 0);
    w_in_b  = (unsigned short*)(ws + 32*MiB);
    delta_b = (unsigned short*)(ws + 0);
    x_b     = (unsigned short*)(ws + 64*MiB);
    wxp_b   = (unsigned short*)(ws + 64*MiB);
    wdt_b   = (unsigned short*)(ws + 66*MiB);
    wout_b  = (unsigned short*)(ws + 68*MiB);
    xdbl    = (float*)         (ws + 84*MiB);
    dtr_b   = (unsigned short*)(ws + 90*MiB);
    Sbuf    = (float*)         (ws + 92*MiB);
    Xin     = (float*)         (ws + 108*MiB);
    sdelta  = (float*)         (ws + 124*MiB);
    z_b     = (unsigned short*)(ws + 128*MiB);
    u_b     = (unsigned short*)(ws + 192*MiB);
    y_b     = u_b;
  }

  // 1) converts needed for in_proj
  cvt_bf16_kernel<<<(MROWS*DMODEL)/1024, 256, 0, stream>>>(hs, hs_b, MROWS*DMODEL);
  cvt_bf16_kernel<<<(2*DINNER*DMODEL)/1024, 256, 0, stream>>>(w_in, w_in_b, 2*DINNER*DMODEL);

  // 2) in_proj: (8192x2048)@(8192x2048)^T, 256^2 tiles -> 32x32=1024 blocks
  gemm256<0><<<1024, 512, 0, stream>>>(hs_b, w_in_b, DMODEL, 32, 0,
                                       x_b, z_b, nullptr);
  // 3) new_conv_state
  conv_state_kernel<<<256, 256, 0, stream>>>(x_b, out + (size_t)MROWS*DMODEL);
  // 4) conv + silu -> u (x dead afterwards)
  conv_silu_kernel<<<(MROWS*512)/256, 256, 0, stream>>>(x_b, conv_w, conv_b, u_b);

  // 5) weight converts (into dead-x slot in aliased mode)
  cvt_bf16_kernel<<<(160*DINNER)/1024, 256, 0, stream>>>(w_xp, wxp_b, 160*DINNER);
  cvt_bf16_kernel<<<(DINNER*DTRANK)/1024, 256, 0, stream>>>(w_dt, wdt_b, DINNER*DTRANK);
  cvt_bf16_kernel<<<(DMODEL*DINNER)/1024, 256, 0, stream>>>(w_out, wout_b, DMODEL*DINNER);

  // 6) x_proj -> xdbl fp32
  gemm_bt<1><<<dim3(2,64), 256, 0, stream>>>(u_b, wxp_b, DINNER, 160,
                                             xdbl, nullptr, nullptr, 160);
  // 7) dtr bf16
  cvt_dtr_kernel<<<(MROWS*32)/256, 256, 0, stream>>>(xdbl, dtr_b);
  // 8) dt_proj + softplus -> delta
  gemm_bt<2><<<dim3(32,64), 256, 0, stream>>>(dtr_b, wdt_b, DTRANK, DINNER,
                                              nullptr, delta_b, dt_bias, DINNER);
  // 9) chunked scan
  scan_part1<<<1024, 256, 0, stream>>>(delta_b, u_b, xdbl, Amat, Sbuf, sdelta);
  scan_part2<<<1024, 256, 0, stream>>>(Sbuf, sdelta, Amat, Xin,
                                       out + (size_t)MROWS*DMODEL + NB*DINNER*4);
  scan_part3<<<1024, 256, 0, stream>>>(delta_b, u_b, z_b, xdbl, Amat, Dvec, Xin, y_b);
  // 10) out_proj: (8192x4096)@(2048x4096)^T, 32x8=256 blocks
  gemm256<3><<<256, 512, 0, stream>>>(y_b, wout_b, DINNER, 8, DMODEL,
                                      nullptr, nullptr, out);
}

// Round 7
// 912.459 us; speedup vs baseline: 5.0875x; 1.1078x over previous
//
#include <hip/hip_runtime.h>
#include <hip/hip_bf16.h>
#include <math.h>

typedef __attribute__((ext_vector_type(4))) float fvec4;
typedef __attribute__((ext_vector_type(2))) float fvec2;
typedef __attribute__((ext_vector_type(4))) int ivec4;
typedef __attribute__((ext_vector_type(4))) unsigned short usvec4;
typedef __attribute__((ext_vector_type(8))) short bf16x8;

#define SEQ 2048
#define DMODEL 2048
#define DINNER 4096
#define DSTATE 16
#define DTRANK 128
#define NB 4
#define MROWS (NB*SEQ)  // 8192
#define NCHUNK 16
#define LC (SEQ/NCHUNK) // 128

__device__ __forceinline__ float bf2f(unsigned short h){
  union{unsigned int u; float f;} v; v.u = ((unsigned int)h)<<16; return v.f;
}
__device__ __forceinline__ unsigned short f2bf(float f){
  union{float f; unsigned int u;} v; v.f=f;
  unsigned int r = v.u + 0x7fffu + ((v.u>>16)&1u);
  return (unsigned short)(r>>16);
}
__device__ __forceinline__ void async16(const void* g, void* l){
  __builtin_amdgcn_global_load_lds((const __attribute__((address_space(1))) void*)g,
                                   (__attribute__((address_space(3))) void*)l, 16, 0, 0);
}
__device__ __forceinline__ float sigf(float x){ return 1.f/(1.f+__expf(-x)); }

// ---------------- fp32 -> bf16 convert ----------------
__global__ void cvt_bf16_kernel(const float* __restrict__ in, unsigned short* __restrict__ out, int n){
  int i = (blockIdx.x*256 + threadIdx.x)*4;
  if (i >= n) return;
  fvec4 v = *(const fvec4*)(in + i);
  usvec4 o;
  o[0]=f2bf(v[0]); o[1]=f2bf(v[1]); o[2]=f2bf(v[2]); o[3]=f2bf(v[3]);
  *(usvec4*)(out + i) = o;
}

// ================= 256x256 GEMM (C = A * B^T), 4-slot ring =================
// BK=32, 4-slot LDS ring (128 KiB), ONE barrier per K-step, counted vmcnt:
//   [vmcnt(8): tile kt's 4 loads (oldest of <=12) done] -> [s_barrier: kt
//   staged by ALL waves; slot (kt-1)&3's readers done] -> [stage kt+3 into
//   slot (kt+3)&3 = (kt-1)&3] -> [read slot kt&3, MFMA].
// The waited-on tile was issued 3 iterations (~3700cy) earlier -> vmcnt(8) is
// effectively free (r6's vmcnt(0) waited on loads issued 1 phase earlier).
// Race-free: a wave passes barrier kt only after its iter-(kt-1) ds_reads
// retired (lgkm before MFMA), and staging of that slot is issued post-barrier.
// T2 swizzle (0 conflicts, r5/r6-verified). T1 XCD swizzle.
// (512,2): 256-reg budget. (512,4) spills acc -> 9x regression (r5).
// MODE 0: split x/z bf16 at col 4096 (in_proj). MODE 3: fp32 store (out_proj).
template<int MODE>
__global__ __launch_bounds__(512, 2) void gemm256(
    const unsigned short* __restrict__ A,
    const unsigned short* __restrict__ B,
    int K, int nbx, int ldc,
    unsigned short* __restrict__ Cb1,
    unsigned short* __restrict__ Cb2,
    float* __restrict__ Cf)
{
  __shared__ __align__(16) unsigned short lds[65536];  // 4 slots x 32 KiB
  char* ldsc = (char*)lds;
  const int t = threadIdx.x;

  // T1: XCD swizzle (gridDim.x % 8 == 0 for all uses)
  const int nwg = gridDim.x;
  const int cpx = nwg >> 3;
  const int bid = blockIdx.x;
  const int swzb = (bid & 7)*cpx + (bid >> 3);
  const int bx = swzb % nbx, by = swzb / nbx;

  // staging source: pre-apply the LDS swizzle involution to the global source
  // byte ^= ((byte>>7)&3)<<4  (within each operand's 16 KiB region)
  const int bA0 = t*16, bA1 = 8192 + t*16;
  const int sw0 = bA0 ^ (((bA0>>7)&3)<<4);
  const int sw1 = bA1 ^ (((bA1>>7)&3)<<4);
  const int gr0 = sw0>>6, gc0 = (sw0&63)>>1;
  const int gr1 = sw1>>6, gc1 = (sw1&63)>>1;
  const unsigned short* Ab = A + (long)by*256*K;
  const unsigned short* Bb = B + (long)bx*256*K;
  const unsigned short* gA0 = Ab + (long)gr0*K + gc0;
  const unsigned short* gA1 = Ab + (long)gr1*K + gc1;
  const unsigned short* gB0 = Bb + (long)gr0*K + gc0;
  const unsigned short* gB1 = Bb + (long)gr1*K + gc1;

  // fragment read offsets (swizzled): slot = (fr>>1)&3
  const int wid = t>>6, lane = t&63;
  const int wm = wid>>2, wn = wid&3;
  const int fr = lane&15, fc = lane>>4;
  const int cb = (fc<<4) ^ (((fr>>1)&3)<<4);
  const int offA = (wm*128 + fr)*64 + cb;            // + i*1024
  const int offB = 16384 + (wn*64 + fr)*64 + cb;     // + j*1024

  fvec4 acc[8][4];
  #pragma unroll
  for (int i=0;i<8;i++){
    #pragma unroll
    for (int j=0;j<4;j++) acc[i][j] = (fvec4)(0.f);
  }

  const int NKT = K >> 5;
  auto stage = [&](int slot, int k0){
    char* sb = ldsc + slot*32768;
    async16(gA0 + k0, sb + t*16);
    async16(gA1 + k0, sb + 8192 + t*16);
    async16(gB0 + k0, sb + 16384 + t*16);
    async16(gB1 + k0, sb + 24576 + t*16);
  };

  // prologue: 3 tiles in flight (12 outstanding loads)
  stage(0, 0); stage(1, 32); stage(2, 64);

  for (int kt = 0; kt < NKT; ++kt){
    asm volatile("s_waitcnt vmcnt(8)" ::: "memory");  // tile kt's loads done (mine)
    __builtin_amdgcn_s_barrier();                     // kt staged by all; slot (kt-1)&3 readers done
    __builtin_amdgcn_sched_barrier(0);                // nothing below moves above the barrier
    { int ks = kt + 3; if (ks > NKT-1) ks = NKT-1;    // tail: refetch last tile into dead slot
      stage((kt+3)&3, ks*32); }
    __builtin_amdgcn_sched_barrier(0);                // stage issued before ds_reads
    const char* sb = ldsc + (kt&3)*32768;
    bf16x8 af[8], bv[4];
    #pragma unroll
    for (int j=0;j<4;j++) bv[j] = *(const bf16x8*)(sb + offB + j*1024);
    #pragma unroll
    for (int i=0;i<8;i++) af[i] = *(const bf16x8*)(sb + offA + i*1024);
    __builtin_amdgcn_s_setprio(1);
    #pragma unroll
    for (int i=0;i<8;i++){
      #pragma unroll
      for (int j=0;j<4;j++){
        acc[i][j] = __builtin_amdgcn_mfma_f32_16x16x32_bf16(af[i], bv[j], acc[i][j], 0,0,0);
      }
    }
    __builtin_amdgcn_s_setprio(0);
  }

  const long crow0 = (long)by*256 + wm*128;
  const int  ccol0 = bx*256 + wn*64;
  #pragma unroll
  for (int i=0;i<8;i++){
    #pragma unroll
    for (int j=0;j<4;j++){
      #pragma unroll
      for (int q=0;q<4;q++){
        long rg = crow0 + i*16 + fc*4 + q;
        int  cg = ccol0 + j*16 + fr;
        float v = acc[i][j][q];
        if (MODE==0){
          if (cg < DINNER) Cb1[rg*DINNER + cg] = f2bf(v);
          else             Cb2[rg*DINNER + (cg-DINNER)] = f2bf(v);
        } else {
          Cf[rg*(long)ldc + cg] = v;
        }
      }
    }
  }
}

// ---------------- m97-style 128x128 GEMM for the small projections ----------------
// MODE 1: fp32 store, guard col<Nreal (x_proj)
// MODE 2: softplus(v+bias) -> bf16 (dt_proj -> delta)
template<int MODE>
__global__ __launch_bounds__(256) void gemm_bt(
    const unsigned short* __restrict__ A,
    const unsigned short* __restrict__ B,
    int K, int Nreal,
    float* __restrict__ Cf,
    unsigned short* __restrict__ Cb1,
    const float* __restrict__ bias,
    int ldc)
{
  __shared__ __align__(16) unsigned short As[128*32];
  __shared__ __align__(16) unsigned short Bs[128*32];
  const int t = threadIdx.x;
  const int bx = blockIdx.x, by = blockIdx.y;
  const int wave = t>>6, lane = t&63;
  const int wr = (wave>>1)*64, wc = (wave&1)*64;
  const int fr = lane&15, fc = lane>>4;
  fvec4 acc[4][4];
  #pragma unroll
  for(int i=0;i<4;i++){
    #pragma unroll
    for(int j=0;j<4;j++){ acc[i][j] = (fvec4)(0.f); }
  }
  const int srow = t>>2;
  const int scol = (t&3)*8;
  long rowA = (long)by*128 + srow;
  int rB0 = bx*128 + srow;      if (rB0 > Nreal-1) rB0 = Nreal-1;
  int rB1 = bx*128 + 64 + srow; if (rB1 > Nreal-1) rB1 = Nreal-1;
  const unsigned short* gA0 = A + rowA*(long)K + scol;
  const unsigned short* gA1 = gA0 + 64L*K;
  const unsigned short* gB0 = B + (long)rB0*K + scol;
  const unsigned short* gB1 = B + (long)rB1*K + scol;
  unsigned short* lA0 = &As[t*8];
  unsigned short* lA1 = &As[2048 + t*8];
  unsigned short* lB0 = &Bs[t*8];
  unsigned short* lB1 = &Bs[2048 + t*8];

  for (int k0 = 0; k0 < K; k0 += 32){
    async16(gA0 + k0, lA0);
    async16(gA1 + k0, lA1);
    async16(gB0 + k0, lB0);
    async16(gB1 + k0, lB1);
    __syncthreads();
    bf16x8 af[4], bv[4];
    #pragma unroll
    for(int i=0;i<4;i++){
      af[i] = *(const bf16x8*)&As[(wr + i*16 + fr)*32 + fc*8];
      bv[i] = *(const bf16x8*)&Bs[(wc + i*16 + fr)*32 + fc*8];
    }
    #pragma unroll
    for(int i=0;i<4;i++){
      #pragma unroll
      for(int j=0;j<4;j++){
        acc[i][j] = __builtin_amdgcn_mfma_f32_16x16x32_bf16(af[i], bv[j], acc[i][j], 0,0,0);
      }
    }
    __syncthreads();
  }

  const long crow0 = (long)by*128 + wr;
  const int ccol0 = bx*128 + wc;
  #pragma unroll
  for(int i=0;i<4;i++){
    #pragma unroll
    for(int j=0;j<4;j++){
      #pragma unroll
      for(int q=0;q<4;q++){
        long rg = crow0 + i*16 + fc*4 + q;
        int  cg = ccol0 + j*16 + fr;
        float v = acc[i][j][q];
        if (MODE==1){
          if (cg < Nreal) Cf[rg*ldc + cg] = v;
        } else if (MODE==2){
          float x = v + bias[cg];
          float sp = (x > 20.f) ? x : log1pf(__expf(x));
          Cb1[rg*ldc + cg] = f2bf(sp);
        }
      }
    }
  }
}

// ---------------- depthwise causal conv(4) + bias + SiLU ----------------
__global__ __launch_bounds__(256) void conv_silu_kernel(
    const unsigned short* __restrict__ xb, const float* __restrict__ w,
    const float* __restrict__ bias, unsigned short* __restrict__ ub)
{
  int gid = blockIdx.x*256 + threadIdx.x;
  int d0 = (gid & 511)*8;
  long m = gid >> 9;
  int l = (int)(m & (SEQ-1));
  fvec4 w4[8];
  #pragma unroll
  for(int k=0;k<8;k++) w4[k] = *(const fvec4*)&w[(d0+k)*4];
  float acc[8];
  fvec4 b0 = *(const fvec4*)&bias[d0];
  fvec4 b1 = *(const fvec4*)&bias[d0+4];
  acc[0]=b0[0];acc[1]=b0[1];acc[2]=b0[2];acc[3]=b0[3];
  acc[4]=b1[0];acc[5]=b1[1];acc[6]=b1[2];acc[7]=b1[3];
  #pragma unroll
  for(int j=0;j<4;j++){
    int lj = l-3+j;
    if (lj >= 0){
      ivec4 xv = *(const ivec4*)&xb[(m-3+j)*DINNER + d0];
      float xs[8];
      #pragma unroll
      for(int q=0;q<4;q++){
        unsigned int wd = (unsigned int)xv[q];
        xs[2*q]   = bf2f((unsigned short)(wd & 0xffffu));
        xs[2*q+1] = bf2f((unsigned short)(wd >> 16));
      }
      #pragma unroll
      for(int k=0;k<8;k++) acc[k] += xs[k]*w4[k][j];
    }
  }
  ivec4 ov;
  #pragma unroll
  for(int q=0;q<4;q++){
    float y0 = acc[2*q]  * sigf(acc[2*q]);
    float y1 = acc[2*q+1]* sigf(acc[2*q+1]);
    ov[q] = (int)((unsigned)f2bf(y0) | ((unsigned)f2bf(y1) << 16));
  }
  *(ivec4*)&ub[m*DINNER + d0] = ov;
}

// ---------------- new_conv_state ----------------
__global__ void conv_state_kernel(const unsigned short* __restrict__ xb, float* __restrict__ out){
  int i = blockIdx.x*256 + threadIdx.x;
  int b = i >> 14; int r = i & 16383; int dd = r >> 2; int j = r & 3;
  out[i] = bf2f(xb[((long)(b*SEQ + (SEQ-4) + j))*DINNER + dd]);
}

// ---------------- xdbl[:, :128] -> bf16 for dt_proj A ----------------
__global__ void cvt_dtr_kernel(const float* __restrict__ xdbl, unsigned short* __restrict__ dtr){
  int i = blockIdx.x*256 + threadIdx.x;
  long mrow = i >> 5; int c = (i & 31)*4;
  fvec4 v = *(const fvec4*)&xdbl[mrow*160 + c];
  usvec4 o; o[0]=f2bf(v[0]); o[1]=f2bf(v[1]); o[2]=f2bf(v[2]); o[3]=f2bf(v[3]);
  *(usvec4*)&dtr[mrow*DTRANK + c] = o;
}

// ---- exp(dl*a[n]) for n=0..15 when a[n] == -(n+1): powers of e1=exp(-dl).
// 1 transcendental + 15 full-rate muls (vs 16 quarter-rate exps). dl>=0 so
// e1<=1: no overflow, error ~few ulp (<< bf16 threshold).
__device__ __forceinline__ void exp_powers(float dl, float* e){
  float e1 = __expf(-dl);
  float p2 = e1*e1, p3 = p2*e1, p4 = p2*p2;
  float p5 = p4*e1, p6 = p4*p2, p7 = p4*p3, p8 = p4*p4;
  e[0]=e1; e[1]=p2; e[2]=p3; e[3]=p4; e[4]=p5; e[5]=p6; e[6]=p7; e[7]=p8;
  e[8]=p8*e1; e[9]=p8*p2; e[10]=p8*p3; e[11]=p8*p4;
  e[12]=p8*p5; e[13]=p8*p6; e[14]=p8*p7; e[15]=p8*p8;
}

// ================= chunked parallel scan =================
__global__ __launch_bounds__(256) void scan_part1(
    const unsigned short* __restrict__ delta_b,
    const unsigned short* __restrict__ u_b,
    const float* __restrict__ xdbl,
    const float* __restrict__ Amat,
    float* __restrict__ S,
    float* __restrict__ sdelta)
{
  const int t = threadIdx.x;
  const int blk = blockIdx.x;
  const int c = blk & 15, b = (blk>>4)&3, d = (blk>>6)*256 + t;
  float a[16], s[16];
  #pragma unroll
  for (int n=0;n<16;n++){ a[n] = Amat[n*DINNER+d]; s[n]=0.f; }
  bool powA = true;
  #pragma unroll
  for (int n=0;n<16;n++) powA = powA && (a[n] == -(float)(n+1));
  float sd = 0.f;
  const long mbase = (long)b*SEQ + c*LC;

#define S1_BODY(EXPR_E) \
  for (int l=0;l<LC;l++){ \
    long m = mbase + l; \
    float dl = bf2f(delta_b[m*DINNER+d]); \
    float ul = bf2f(u_b[m*DINNER+d]); \
    const float* xb = &xdbl[m*160 + 128]; \
    float dbu = dl*ul; \
    sd += dl; \
    float e[16]; EXPR_E; \
    _Pragma("unroll") \
    for (int g=0; g<4; g++){ \
      fvec4 Bg = *(const fvec4*)(xb + 4*g); \
      _Pragma("unroll") \
      for (int q=0;q<4;q++){ \
        int n = g*4+q; \
        s[n] = e[n]*s[n] + Bg[q]*dbu; \
      } \
    } \
  }

  if (powA){
    S1_BODY(exp_powers(dl, e))
  } else {
    S1_BODY({ _Pragma("unroll") for (int n=0;n<16;n++) e[n] = __expf(dl*a[n]); })
  }
#undef S1_BODY

  const long base = ((long)(b*NCHUNK + c)*DSTATE)*DINNER + d;
  #pragma unroll
  for (int n=0;n<16;n++) S[base + (long)n*DINNER] = s[n];
  sdelta[(long)(b*NCHUNK+c)*DINNER + d] = sd;
}

__global__ __launch_bounds__(256) void scan_part2(
    const float* __restrict__ S,
    const float* __restrict__ sdelta,
    const float* __restrict__ Amat,
    float* __restrict__ Xin,
    float* __restrict__ last_state)
{
  int id = blockIdx.x*256 + threadIdx.x;
  int d = id & (DINNER-1);
  int n = (id>>12) & 15;
  int b = id>>16;
  float a = Amat[n*DINNER+d];
  float X = 0.f;
  #pragma unroll
  for (int c=0;c<NCHUNK;c++){
    long sb = ((long)(b*NCHUNK+c)*DSTATE + n)*DINNER + d;
    Xin[sb] = X;
    float sd = sdelta[(long)(b*NCHUNK+c)*DINNER + d];
    float Sc = S[sb];
    X = __expf(a*sd)*X + Sc;
  }
  last_state[((long)b*DSTATE + n)*DINNER + d] = X;
}

__global__ __launch_bounds__(256) void scan_part3(
    const unsigned short* __restrict__ delta_b,
    const unsigned short* __restrict__ u_b,
    const unsigned short* __restrict__ z_b,
    const float* __restrict__ xdbl,
    const float* __restrict__ Amat,
    const float* __restrict__ Dvec,
    const float* __restrict__ Xin,
    unsigned short* __restrict__ y_b)
{
  const int t = threadIdx.x;
  const int blk = blockIdx.x;
  const int c = blk & 15, b = (blk>>4)&3, d = (blk>>6)*256 + t;
  float a[16], s[16];
  const long xb0 = ((long)(b*NCHUNK + c)*DSTATE)*DINNER + d;
  #pragma unroll
  for (int n=0;n<16;n++){
    a[n] = Amat[n*DINNER+d];
    s[n] = Xin[xb0 + (long)n*DINNER];
  }
  bool powA = true;
  #pragma unroll
  for (int n=0;n<16;n++) powA = powA && (a[n] == -(float)(n+1));
  const float Dd = Dvec[d];
  const long mbase = (long)b*SEQ + c*LC;

#define S3_BODY(EXPR_E) \
  for (int l=0;l<LC;l++){ \
    long m = mbase + l; \
    float dl = bf2f(delta_b[m*DINNER+d]); \
    float ul = bf2f(u_b[m*DINNER+d]); \
    float zl = bf2f(z_b[m*DINNER+d]); \
    const float* xb = &xdbl[m*160 + 128]; \
    float dbu = dl*ul; \
    float y = 0.f; \
    float e[16]; EXPR_E; \
    _Pragma("unroll") \
    for (int g=0; g<4; g++){ \
      fvec4 Bg = *(const fvec4*)(xb + 4*g); \
      fvec4 Cg = *(const fvec4*)(xb + 16 + 4*g); \
      _Pragma("unroll") \
      for (int q=0;q<4;q++){ \
        int n = g*4+q; \
        s[n] = e[n]*s[n] + Bg[q]*dbu; \
        y += Cg[q]*s[n]; \
      } \
    } \
    float yy = y + ul*Dd; \
    float zs = zl*sigf(zl); \
    y_b[m*DINNER+d] = f2bf(yy*zs); \
  }

  if (powA){
    S3_BODY(exp_powers(dl, e))
  } else {
    S3_BODY({ _Pragma("unroll") for (int n=0;n<16;n++) e[n] = __expf(dl*a[n]); })
  }
#undef S3_BODY
}

// ---------------- launcher ----------------
// Aliased 256 MiB layout:
//   Slot A [0,64M):    hs_b(32M)+w_in_b(32M) -> delta(64M) after in_proj
//   Slot B [64,128M):  x(64M) -> after conv: wxp@64 wdt@66 wout@68 xdbl@84
//                      dtr@90 S@92(16M) Xin@108(16M) sdelta@124(1M)
//   Slot C [128,192M): z(64M)
//   Slot D [192,256M): u(64M) -> y written in-place by scan_part3
extern "C" void kernel_launch(void* const* d_in, const int* in_sizes, int n_in,
                              void* d_out, int out_size, void* d_ws, size_t ws_size,
                              hipStream_t stream) {
  const float* hs     = (const float*)d_in[0];
  const float* w_in   = (const float*)d_in[6];
  const float* conv_w = (const float*)d_in[7];
  const float* conv_b = (const float*)d_in[8];
  const float* w_xp   = (const float*)d_in[9];
  const float* w_dt   = (const float*)d_in[10];
  const float* dt_bias= (const float*)d_in[11];
  const float* Amat   = (const float*)d_in[12];
  const float* Dvec   = (const float*)d_in[13];
  const float* w_out  = (const float*)d_in[14];
  float* out = (float*)d_out;

  char* ws = (char*)d_ws;
  const size_t MiB = (size_t)1 << 20;

  unsigned short *hs_b, *w_in_b, *x_b, *z_b, *u_b, *delta_b;
  unsigned short *wxp_b, *wdt_b, *wout_b, *dtr_b, *y_b;
  float *xdbl, *Sbuf, *Xin, *sdelta;

  if (ws_size >= 400*MiB){
    size_t off = 0;
    auto alloc = [&](size_t bytes)->void*{ void* p = ws + off; off += (bytes + 255) & ~(size_t)255; return p; };
    hs_b   = (unsigned short*)alloc((size_t)MROWS*DMODEL*2);
    w_in_b = (unsigned short*)alloc((size_t)2*DINNER*DMODEL*2);
    x_b    = (unsigned short*)alloc((size_t)MROWS*DINNER*2);
    z_b    = (unsigned short*)alloc((size_t)MROWS*DINNER*2);
    u_b    = (unsigned short*)alloc((size_t)MROWS*DINNER*2);
    delta_b= (unsigned short*)alloc((size_t)MROWS*DINNER*2);
    wxp_b  = (unsigned short*)alloc((size_t)160*DINNER*2);
    wdt_b  = (unsigned short*)alloc((size_t)DINNER*DTRANK*2);
    wout_b = (unsigned short*)alloc((size_t)DMODEL*DINNER*2);
    xdbl   = (float*)alloc((size_t)MROWS*160*4);
    dtr_b  = (unsigned short*)alloc((size_t)MROWS*DTRANK*2);
    Sbuf   = (float*)alloc((size_t)NB*NCHUNK*DSTATE*DINNER*4);
    Xin    = (float*)alloc((size_t)NB*NCHUNK*DSTATE*DINNER*4);
    sdelta = (float*)alloc((size_t)NB*NCHUNK*DINNER*4);
    y_b    = x_b;
  } else {
    hs_b    = (unsigned short*)(ws + 0);
    w_in_b  = (unsigned short*)(ws + 32*MiB);
    delta_b = (unsigned short*)(ws + 0);
    x_b     = (unsigned short*)(ws + 64*MiB);
    wxp_b   = (unsigned short*)(ws + 64*MiB);
    wdt_b   = (unsigned short*)(ws + 66*MiB);
    wout_b  = (unsigned short*)(ws + 68*MiB);
    xdbl    = (float*)         (ws + 84*MiB);
    dtr_b   = (unsigned short*)(ws + 90*MiB);
    Sbuf    = (float*)         (ws + 92*MiB);
    Xin     = (float*)         (ws + 108*MiB);
    sdelta  = (float*)         (ws + 124*MiB);
    z_b     = (unsigned short*)(ws + 128*MiB);
    u_b     = (unsigned short*)(ws + 192*MiB);
    y_b     = u_b;
  }

  // 1) converts needed for in_proj
  cvt_bf16_kernel<<<(MROWS*DMODEL)/1024, 256, 0, stream>>>(hs, hs_b, MROWS*DMODEL);
  cvt_bf16_kernel<<<(2*DINNER*DMODEL)/1024, 256, 0, stream>>>(w_in, w_in_b, 2*DINNER*DMODEL);

  // 2) in_proj: (8192x2048)@(8192x2048)^T, 256^2 tiles -> 32x32=1024 blocks
  gemm256<0><<<1024, 512, 0, stream>>>(hs_b, w_in_b, DMODEL, 32, 0,
                                       x_b, z_b, nullptr);
  // 3) new_conv_state
  conv_state_kernel<<<256, 256, 0, stream>>>(x_b, out + (size_t)MROWS*DMODEL);
  // 4) conv + silu -> u (x dead afterwards)
  conv_silu_kernel<<<(MROWS*512)/256, 256, 0, stream>>>(x_b, conv_w, conv_b, u_b);

  // 5) weight converts (into dead-x slot in aliased mode)
  cvt_bf16_kernel<<<(160*DINNER)/1024, 256, 0, stream>>>(w_xp, wxp_b, 160*DINNER);
  cvt_bf16_kernel<<<(DINNER*DTRANK)/1024, 256, 0, stream>>>(w_dt, wdt_b, DINNER*DTRANK);
  cvt_bf16_kernel<<<(DMODEL*DINNER)/1024, 256, 0, stream>>>(w_out, wout_b, DMODEL*DINNER);

  // 6) x_proj -> xdbl fp32
  gemm_bt<1><<<dim3(2,64), 256, 0, stream>>>(u_b, wxp_b, DINNER, 160,
                                             xdbl, nullptr, nullptr, 160);
  // 7) dtr bf16
  cvt_dtr_kernel<<<(MROWS*32)/256, 256, 0, stream>>>(xdbl, dtr_b);
  // 8) dt_proj + softplus -> delta
  gemm_bt<2><<<dim3(32,64), 256, 0, stream>>>(dtr_b, wdt_b, DTRANK, DINNER,
                                              nullptr, delta_b, dt_bias, DINNER);
  // 9) chunked scan
  scan_part1<<<1024, 256, 0, stream>>>(delta_b, u_b, xdbl, Amat, Sbuf, sdelta);
  scan_part2<<<1024, 256, 0, stream>>>(Sbuf, sdelta, Amat, Xin,
                                       out + (size_t)MROWS*DMODEL + NB*DINNER*4);
  scan_part3<<<1024, 256, 0, stream>>>(delta_b, u_b, z_b, xdbl, Amat, Dvec, Xin, y_b);
  // 10) out_proj: (8192x4096)@(2048x4096)^T, 32x8=256 blocks
  gemm256<3><<<256, 512, 0, stream>>>(y_b, wout_b, DINNER, 8, DMODEL,
                                      nullptr, nullptr, out);
}

// Round 8
// 828.083 us; speedup vs baseline: 5.6059x; 1.1019x over previous
//
#include <hip/hip_runtime.h>
#include <hip/hip_bf16.h>
#include <math.h>

typedef __attribute__((ext_vector_type(4))) float fvec4;
typedef __attribute__((ext_vector_type(2))) float fvec2;
typedef __attribute__((ext_vector_type(4))) int ivec4;
typedef __attribute__((ext_vector_type(4))) unsigned short usvec4;
typedef __attribute__((ext_vector_type(8))) short bf16x8;

#define SEQ 2048
#define DMODEL 2048
#define DINNER 4096
#define DSTATE 16
#define DTRANK 128
#define NB 4
#define MROWS (NB*SEQ)  // 8192
#define NCHUNK 16
#define LC (SEQ/NCHUNK) // 128

__device__ __forceinline__ float bf2f(unsigned short h){
  union{unsigned int u; float f;} v; v.u = ((unsigned int)h)<<16; return v.f;
}
__device__ __forceinline__ unsigned short f2bf(float f){
  union{float f; unsigned int u;} v; v.f=f;
  unsigned int r = v.u + 0x7fffu + ((v.u>>16)&1u);
  return (unsigned short)(r>>16);
}
__device__ __forceinline__ void async16(const void* g, void* l){
  __builtin_amdgcn_global_load_lds((const __attribute__((address_space(1))) void*)g,
                                   (__attribute__((address_space(3))) void*)l, 16, 0, 0);
}
__device__ __forceinline__ float sigf(float x){ return 1.f/(1.f+__expf(-x)); }

// ---------------- fp32 -> bf16 convert ----------------
__global__ void cvt_bf16_kernel(const float* __restrict__ in, unsigned short* __restrict__ out, int n){
  int i = (blockIdx.x*256 + threadIdx.x)*4;
  if (i >= n) return;
  fvec4 v = *(const fvec4*)(in + i);
  usvec4 o;
  o[0]=f2bf(v[0]); o[1]=f2bf(v[1]); o[2]=f2bf(v[2]); o[3]=f2bf(v[3]);
  *(usvec4*)(out + i) = o;
}

// ================= 256x256 GEMM (C = A * B^T), 8-phase-style =================
// BK=64, 2 dbuf x 64 KiB (A 32K + B 32K each), 4 phases per K-tile, each:
//   {ds_read quadrant frags; stage half-tiles; s_barrier; lgkmcnt(0);
//    setprio(1); 16 MFMA; setprio(0); s_barrier}
// vmcnt(0) ONLY at phase 4 — covers this iter's 8 stage loads (issued phases
// 1-2, ~2.5 phases ~1500cy earlier => effectively free, never a mid-pipe drain).
// Race-freedom: dbuf (kt+1)&1 staged in iter kt was last READ in iter kt-1,
// whose ds_reads retired (lgkmcnt0 before MFMA) before its final barrier;
// the phase-4 {vmcnt(0); barrier} certifies tile kt+1 staged chip-wide before
// iter kt+1's phase-1 ds_reads. Quadrant order (0,0)(0,1)(1,1)(1,0) reuses
// A frags across P1/P2 and P3/P4 => 28 ds_read_b128 per wave per K-tile,
// frag VGPR stays 48 (no r5-style spill).
// Swizzle (128B rows): byte = r*128 + ((c ^ ((r&7)<<4)))  => 16B-slot index
// (4k+fc)^(fr&7): 8 slots, 2-way max. Same involution pre-applied to the
// global staging source (LDS dest linear, rule #21).
// (512,2): 256-reg budget; acc in AGPR (128) + ~110 VGPR.
// MODE 0: split x/z bf16 at col 4096 (in_proj). MODE 3: fp32 store (out_proj).
template<int MODE>
__global__ __launch_bounds__(512, 2) void gemm256(
    const unsigned short* __restrict__ A,
    const unsigned short* __restrict__ B,
    int K, int nbx, int ldc,
    unsigned short* __restrict__ Cb1,
    unsigned short* __restrict__ Cb2,
    float* __restrict__ Cf)
{
  __shared__ __align__(16) unsigned short lds[65536];  // 128 KiB: 2 dbuf x 64KB
  char* ldsc = (char*)lds;
  const int t = threadIdx.x;

  // T1: XCD swizzle (gridDim.x % 8 == 0 for all uses)
  const int nwg = gridDim.x;
  const int cpx = nwg >> 3;
  const int bid = blockIdx.x;
  const int swzb = (bid & 7)*cpx + (bid >> 3);
  const int bx = swzb % nbx, by = swzb / nbx;

  const int wid = t>>6, lane = t&63;
  const int wm = wid>>2, wn = wid&3;
  const int fr = lane&15, fc = lane>>4;
  const int x0 = ((fc ^ (fr&7))<<4);          // k-sub 0 swizzled col bytes
  const int x1 = (((4+fc) ^ (fr&7))<<4);      // k-sub 1
  const int arowB = (wm*128 + fr)*128;                 // + ih*8192 + i*2048
  const int browB = 32768 + (wn*64 + fr)*128;          // + jh*4096 + j*2048

  // staging source (pre-swizzled): thread t covers rows r0,r0+64 of a 128-row
  // half at element col cel (16B aligned), LDS dest linear t*16 / 8192+t*16.
  const int r0 = t>>3;
  const int cel = ((((t&7) ^ (r0&7))<<4))>>1;
  const unsigned short* Ab = A + (long)by*256*K;
  const unsigned short* Bb = B + (long)bx*256*K;
  const unsigned short* gA0 = Ab + (long)r0*K + cel;        // A half 0
  const unsigned short* gA1 = Ab + (long)(128+r0)*K + cel;  // A half 1
  const unsigned short* gB0 = Bb + (long)r0*K + cel;
  const unsigned short* gB1 = Bb + (long)(128+r0)*K + cel;
  const int dL0 = t*16, dL1 = 8192 + t*16;

  fvec4 acc[8][4];
  #pragma unroll
  for (int i=0;i<8;i++){
    #pragma unroll
    for (int j=0;j<4;j++) acc[i][j] = (fvec4)(0.f);
  }

  const int NKT = K >> 6;
  const long K64 = 64L*K;

#define STAGE_A(nb_, k0_) { \
    async16(gA0 + (k0_), (nb_) + dL0); async16(gA0 + (k0_) + K64, (nb_) + dL1); \
    async16(gA1 + (k0_), (nb_) + 16384 + dL0); async16(gA1 + (k0_) + K64, (nb_) + 16384 + dL1); }
#define STAGE_B(nb_, k0_) { \
    async16(gB0 + (k0_), (nb_) + 32768 + dL0); async16(gB0 + (k0_) + K64, (nb_) + 32768 + dL1); \
    async16(gB1 + (k0_), (nb_) + 49152 + dL0); async16(gB1 + (k0_) + K64, (nb_) + 49152 + dL1); }

  bf16x8 af[8], bv[4];
#define RD_A(IH) { _Pragma("unroll") for (int i=0;i<4;i++){ \
    const char* p_ = db + arowB + (IH)*8192 + i*2048; \
    af[i*2]   = *(const bf16x8*)(p_ + x0); \
    af[i*2+1] = *(const bf16x8*)(p_ + x1); }}
#define RD_B(JH) { _Pragma("unroll") for (int j=0;j<2;j++){ \
    const char* p_ = db + browB + (JH)*4096 + j*2048; \
    bv[j*2]   = *(const bf16x8*)(p_ + x0); \
    bv[j*2+1] = *(const bf16x8*)(p_ + x1); }}
#define BARR { __builtin_amdgcn_s_barrier(); __builtin_amdgcn_sched_barrier(0); }
#define LGKM0 { asm volatile("s_waitcnt lgkmcnt(0)" ::: "memory"); __builtin_amdgcn_sched_barrier(0); }
#define PH_MMA(IB, JB) { \
    __builtin_amdgcn_s_setprio(1); \
    _Pragma("unroll") for (int i=0;i<4;i++){ \
      _Pragma("unroll") for (int j=0;j<2;j++){ \
        acc[(IB)+i][(JB)+j] = __builtin_amdgcn_mfma_f32_16x16x32_bf16(af[i*2],   bv[j*2],   acc[(IB)+i][(JB)+j], 0,0,0); \
        acc[(IB)+i][(JB)+j] = __builtin_amdgcn_mfma_f32_16x16x32_bf16(af[i*2+1], bv[j*2+1], acc[(IB)+i][(JB)+j], 0,0,0); \
      }} \
    __builtin_amdgcn_s_setprio(0); }

  // prologue: stage tile 0 into dbuf 0, certify chip-wide
  STAGE_A(ldsc, 0); STAGE_B(ldsc, 0);
  asm volatile("s_waitcnt vmcnt(0)" ::: "memory");
  BARR;

  for (int kt = 0; kt < NKT; ++kt){
    const char* db = ldsc + (kt&1)*65536;
    char* nb = ldsc + ((kt+1)&1)*65536;
    int ks = kt + 1; if (ks > NKT-1) ks = NKT-1;   // tail: dead re-stage
    const int k0 = ks*64;
    // ---- P1: quadrant (ih0, jh0)
    RD_A(0); RD_B(0);
    STAGE_A(nb, k0);
    BARR; LGKM0;
    PH_MMA(0, 0);
    BARR;
    // ---- P2: (ih0, jh1) — reuse af
    RD_B(1);
    STAGE_B(nb, k0);
    BARR; LGKM0;
    PH_MMA(0, 2);
    BARR;
    // ---- P3: (ih1, jh1) — reuse bv
    RD_A(1);
    BARR; LGKM0;
    PH_MMA(4, 2);
    BARR;
    // ---- P4: (ih1, jh0)
    RD_B(0);
    asm volatile("s_waitcnt vmcnt(0)" ::: "memory");  // this iter's 8 stage loads done
    BARR; LGKM0;
    PH_MMA(4, 0);
    BARR;
  }
#undef STAGE_A
#undef STAGE_B
#undef RD_A
#undef RD_B
#undef BARR
#undef LGKM0
#undef PH_MMA

  const long crow0 = (long)by*256 + wm*128;
  const int  ccol0 = bx*256 + wn*64;
  #pragma unroll
  for (int i=0;i<8;i++){
    #pragma unroll
    for (int j=0;j<4;j++){
      #pragma unroll
      for (int q=0;q<4;q++){
        long rg = crow0 + i*16 + fc*4 + q;
        int  cg = ccol0 + j*16 + fr;
        float v = acc[i][j][q];
        if (MODE==0){
          if (cg < DINNER) Cb1[rg*DINNER + cg] = f2bf(v);
          else             Cb2[rg*DINNER + (cg-DINNER)] = f2bf(v);
        } else {
          Cf[rg*(long)ldc + cg] = v;
        }
      }
    }
  }
}

// ---------------- m97-style 128x128 GEMM for the small projections ----------------
// MODE 2: softplus(v+bias) -> bf16 (dt_proj -> delta)
// MODE 4: split-K partial fp32 store (x_proj), z = blockIdx.z K-slice
template<int MODE>
__global__ __launch_bounds__(256) void gemm_bt(
    const unsigned short* __restrict__ A,
    const unsigned short* __restrict__ B,
    int lda, int Kloop, int Nreal,
    float* __restrict__ Cf,
    unsigned short* __restrict__ Cb1,
    const float* __restrict__ bias,
    int ldc)
{
  __shared__ __align__(16) unsigned short As[128*32];
  __shared__ __align__(16) unsigned short Bs[128*32];
  const int t = threadIdx.x;
  const int bx = blockIdx.x, by = blockIdx.y;
  const long koff = (MODE==4) ? (long)blockIdx.z * Kloop : 0;
  const int wave = t>>6, lane = t&63;
  const int wr = (wave>>1)*64, wc = (wave&1)*64;
  const int fr = lane&15, fc = lane>>4;
  fvec4 acc[4][4];
  #pragma unroll
  for(int i=0;i<4;i++){
    #pragma unroll
    for(int j=0;j<4;j++){ acc[i][j] = (fvec4)(0.f); }
  }
  const int srow = t>>2;
  const int scol = (t&3)*8;
  long rowA = (long)by*128 + srow;
  int rB0 = bx*128 + srow;      if (rB0 > Nreal-1) rB0 = Nreal-1;
  int rB1 = bx*128 + 64 + srow; if (rB1 > Nreal-1) rB1 = Nreal-1;
  const unsigned short* gA0 = A + rowA*(long)lda + scol + koff;
  const unsigned short* gA1 = gA0 + 64L*lda;
  const unsigned short* gB0 = B + (long)rB0*lda + scol + koff;
  const unsigned short* gB1 = B + (long)rB1*lda + scol + koff;
  unsigned short* lA0 = &As[t*8];
  unsigned short* lA1 = &As[2048 + t*8];
  unsigned short* lB0 = &Bs[t*8];
  unsigned short* lB1 = &Bs[2048 + t*8];

  for (int k0 = 0; k0 < Kloop; k0 += 32){
    async16(gA0 + k0, lA0);
    async16(gA1 + k0, lA1);
    async16(gB0 + k0, lB0);
    async16(gB1 + k0, lB1);
    __syncthreads();
    bf16x8 af[4], bv[4];
    #pragma unroll
    for(int i=0;i<4;i++){
      af[i] = *(const bf16x8*)&As[(wr + i*16 + fr)*32 + fc*8];
      bv[i] = *(const bf16x8*)&Bs[(wc + i*16 + fr)*32 + fc*8];
    }
    #pragma unroll
    for(int i=0;i<4;i++){
      #pragma unroll
      for(int j=0;j<4;j++){
        acc[i][j] = __builtin_amdgcn_mfma_f32_16x16x32_bf16(af[i], bv[j], acc[i][j], 0,0,0);
      }
    }
    __syncthreads();
  }

  const long crow0 = (long)by*128 + wr;
  const int ccol0 = bx*128 + wc;
  float* Cfz = (MODE==4) ? (Cf + (long)blockIdx.z * MROWS * ldc) : Cf;
  #pragma unroll
  for(int i=0;i<4;i++){
    #pragma unroll
    for(int j=0;j<4;j++){
      #pragma unroll
      for(int q=0;q<4;q++){
        long rg = crow0 + i*16 + fc*4 + q;
        int  cg = ccol0 + j*16 + fr;
        float v = acc[i][j][q];
        if (MODE==4){
          if (cg < Nreal) Cfz[rg*ldc + cg] = v;
        } else if (MODE==2){
          float x = v + bias[cg];
          float sp = (x > 20.f) ? x : log1pf(__expf(x));
          Cb1[rg*ldc + cg] = f2bf(sp);
        }
      }
    }
  }
}

// ---------------- reduce x_proj partials + emit dtr bf16 ----------------
__global__ void reduce_xproj(const float* __restrict__ part,
                             float* __restrict__ xdbl,
                             unsigned short* __restrict__ dtr){
  int i = blockIdx.x*256 + threadIdx.x;           // x4 elems, 8192*160/4 total
  long base = (long)i*4;
  fvec4 s = *(const fvec4*)&part[base];
  #pragma unroll
  for (int z=1; z<4; z++){
    fvec4 p = *(const fvec4*)&part[(long)z*MROWS*160 + base];
    s[0]+=p[0]; s[1]+=p[1]; s[2]+=p[2]; s[3]+=p[3];
  }
  *(fvec4*)&xdbl[base] = s;
  long mrow = base / 160;
  int c = (int)(base - mrow*160);
  if (c < DTRANK){
    usvec4 o; o[0]=f2bf(s[0]); o[1]=f2bf(s[1]); o[2]=f2bf(s[2]); o[3]=f2bf(s[3]);
    *(usvec4*)&dtr[mrow*DTRANK + c] = o;
  }
}

// ---------------- depthwise causal conv(4) + bias + SiLU ----------------
__global__ __launch_bounds__(256) void conv_silu_kernel(
    const unsigned short* __restrict__ xb, const float* __restrict__ w,
    const float* __restrict__ bias, unsigned short* __restrict__ ub)
{
  int gid = blockIdx.x*256 + threadIdx.x;
  int d0 = (gid & 511)*8;
  long m = gid >> 9;
  int l = (int)(m & (SEQ-1));
  fvec4 w4[8];
  #pragma unroll
  for(int k=0;k<8;k++) w4[k] = *(const fvec4*)&w[(d0+k)*4];
  float acc[8];
  fvec4 b0 = *(const fvec4*)&bias[d0];
  fvec4 b1 = *(const fvec4*)&bias[d0+4];
  acc[0]=b0[0];acc[1]=b0[1];acc[2]=b0[2];acc[3]=b0[3];
  acc[4]=b1[0];acc[5]=b1[1];acc[6]=b1[2];acc[7]=b1[3];
  #pragma unroll
  for(int j=0;j<4;j++){
    int lj = l-3+j;
    if (lj >= 0){
      ivec4 xv = *(const ivec4*)&xb[(m-3+j)*DINNER + d0];
      float xs[8];
      #pragma unroll
      for(int q=0;q<4;q++){
        unsigned int wd = (unsigned int)xv[q];
        xs[2*q]   = bf2f((unsigned short)(wd & 0xffffu));
        xs[2*q+1] = bf2f((unsigned short)(wd >> 16));
      }
      #pragma unroll
      for(int k=0;k<8;k++) acc[k] += xs[k]*w4[k][j];
    }
  }
  ivec4 ov;
  #pragma unroll
  for(int q=0;q<4;q++){
    float y0 = acc[2*q]  * sigf(acc[2*q]);
    float y1 = acc[2*q+1]* sigf(acc[2*q+1]);
    ov[q] = (int)((unsigned)f2bf(y0) | ((unsigned)f2bf(y1) << 16));
  }
  *(ivec4*)&ub[m*DINNER + d0] = ov;
}

// ---------------- new_conv_state ----------------
__global__ void conv_state_kernel(const unsigned short* __restrict__ xb, float* __restrict__ out){
  int i = blockIdx.x*256 + threadIdx.x;
  int b = i >> 14; int r = i & 16383; int dd = r >> 2; int j = r & 3;
  out[i] = bf2f(xb[((long)(b*SEQ + (SEQ-4) + j))*DINNER + dd]);
}

// ---- exp(dl*a[n]) for a[n] == -(n+1): powers of e1=exp(-dl) ----
__device__ __forceinline__ void exp_powers(float dl, float* e){
  float e1 = __expf(-dl);
  float p2 = e1*e1, p3 = p2*e1, p4 = p2*p2;
  float p5 = p4*e1, p6 = p4*p2, p7 = p4*p3, p8 = p4*p4;
  e[0]=e1; e[1]=p2; e[2]=p3; e[3]=p4; e[4]=p5; e[5]=p6; e[6]=p7; e[7]=p8;
  e[8]=p8*e1; e[9]=p8*p2; e[10]=p8*p3; e[11]=p8*p4;
  e[12]=p8*p5; e[13]=p8*p6; e[14]=p8*p7; e[15]=p8*p8;
}

// ================= chunked parallel scan =================
__global__ __launch_bounds__(256) void scan_part1(
    const unsigned short* __restrict__ delta_b,
    const unsigned short* __restrict__ u_b,
    const float* __restrict__ xdbl,
    const float* __restrict__ Amat,
    float* __restrict__ S,
    float* __restrict__ sdelta)
{
  const int t = threadIdx.x;
  const int blk = blockIdx.x;
  const int c = blk & 15, b = (blk>>4)&3, d = (blk>>6)*256 + t;
  float a[16], s[16];
  #pragma unroll
  for (int n=0;n<16;n++){ a[n] = Amat[n*DINNER+d]; s[n]=0.f; }
  bool powA = true;
  #pragma unroll
  for (int n=0;n<16;n++) powA = powA && (a[n] == -(float)(n+1));
  float sd = 0.f;
  const long mbase = (long)b*SEQ + c*LC;

#define S1_BODY(EXPR_E) \
  for (int l=0;l<LC;l++){ \
    long m = mbase + l; \
    float dl = bf2f(delta_b[m*DINNER+d]); \
    float ul = bf2f(u_b[m*DINNER+d]); \
    const float* xb = &xdbl[m*160 + 128]; \
    float dbu = dl*ul; \
    sd += dl; \
    float e[16]; EXPR_E; \
    _Pragma("unroll") \
    for (int g=0; g<4; g++){ \
      fvec4 Bg = *(const fvec4*)(xb + 4*g); \
      _Pragma("unroll") \
      for (int q=0;q<4;q++){ \
        int n = g*4+q; \
        s[n] = e[n]*s[n] + Bg[q]*dbu; \
      } \
    } \
  }

  if (powA){
    S1_BODY(exp_powers(dl, e))
  } else {
    S1_BODY({ _Pragma("unroll") for (int n=0;n<16;n++) e[n] = __expf(dl*a[n]); })
  }
#undef S1_BODY

  const long base = ((long)(b*NCHUNK + c)*DSTATE)*DINNER + d;
  #pragma unroll
  for (int n=0;n<16;n++) S[base + (long)n*DINNER] = s[n];
  sdelta[(long)(b*NCHUNK+c)*DINNER + d] = sd;
}

__global__ __launch_bounds__(256) void scan_part2(
    const float* __restrict__ S,
    const float* __restrict__ sdelta,
    const float* __restrict__ Amat,
    float* __restrict__ Xin,
    float* __restrict__ last_state)
{
  int id = blockIdx.x*256 + threadIdx.x;
  int d = id & (DINNER-1);
  int n = (id>>12) & 15;
  int b = id>>16;
  float a = Amat[n*DINNER+d];
  float X = 0.f;
  #pragma unroll
  for (int c=0;c<NCHUNK;c++){
    long sb = ((long)(b*NCHUNK+c)*DSTATE + n)*DINNER + d;
    Xin[sb] = X;
    float sd = sdelta[(long)(b*NCHUNK+c)*DINNER + d];
    float Sc = S[sb];
    X = __expf(a*sd)*X + Sc;
  }
  last_state[((long)b*DSTATE + n)*DINNER + d] = X;
}

__global__ __launch_bounds__(256) void scan_part3(
    const unsigned short* __restrict__ delta_b,
    const unsigned short* __restrict__ u_b,
    const unsigned short* __restrict__ z_b,
    const float* __restrict__ xdbl,
    const float* __restrict__ Amat,
    const float* __restrict__ Dvec,
    const float* __restrict__ Xin,
    unsigned short* __restrict__ y_b)
{
  const int t = threadIdx.x;
  const int blk = blockIdx.x;
  const int c = blk & 15, b = (blk>>4)&3, d = (blk>>6)*256 + t;
  float a[16], s[16];
  const long xb0 = ((long)(b*NCHUNK + c)*DSTATE)*DINNER + d;
  #pragma unroll
  for (int n=0;n<16;n++){
    a[n] = Amat[n*DINNER+d];
    s[n] = Xin[xb0 + (long)n*DINNER];
  }
  bool powA = true;
  #pragma unroll
  for (int n=0;n<16;n++) powA = powA && (a[n] == -(float)(n+1));
  const float Dd = Dvec[d];
  const long mbase = (long)b*SEQ + c*LC;

#define S3_BODY(EXPR_E) \
  for (int l=0;l<LC;l++){ \
    long m = mbase + l; \
    float dl = bf2f(delta_b[m*DINNER+d]); \
    float ul = bf2f(u_b[m*DINNER+d]); \
    float zl = bf2f(z_b[m*DINNER+d]); \
    const float* xb = &xdbl[m*160 + 128]; \
    float dbu = dl*ul; \
    float y = 0.f; \
    float e[16]; EXPR_E; \
    _Pragma("unroll") \
    for (int g=0; g<4; g++){ \
      fvec4 Bg = *(const fvec4*)(xb + 4*g); \
      fvec4 Cg = *(const fvec4*)(xb + 16 + 4*g); \
      _Pragma("unroll") \
      for (int q=0;q<4;q++){ \
        int n = g*4+q; \
        s[n] = e[n]*s[n] + Bg[q]*dbu; \
        y += Cg[q]*s[n]; \
      } \
    } \
    float yy = y + ul*Dd; \
    float zs = zl*sigf(zl); \
    y_b[m*DINNER+d] = f2bf(yy*zs); \
  }

  if (powA){
    S3_BODY(exp_powers(dl, e))
  } else {
    S3_BODY({ _Pragma("unroll") for (int n=0;n<16;n++) e[n] = __expf(dl*a[n]); })
  }
#undef S3_BODY
}

// ---------------- launcher ----------------
// Aliased 256 MiB layout:
//   Slot A [0,64M):    hs_b(32M)+w_in_b(32M) -> xpart(21M, step 6-7) ->
//                      delta(64M, step 8+)
//   Slot B [64,128M):  x(64M) -> after conv: wxp@64 wdt@66 wout@68 xdbl@84
//                      dtr@90 S@92(16M) Xin@108(16M) sdelta@124(1M)
//   Slot C [128,192M): z(64M)
//   Slot D [192,256M): u(64M) -> y written in-place by scan_part3
extern "C" void kernel_launch(void* const* d_in, const int* in_sizes, int n_in,
                              void* d_out, int out_size, void* d_ws, size_t ws_size,
                              hipStream_t stream) {
  const float* hs     = (const float*)d_in[0];
  const float* w_in   = (const float*)d_in[6];
  const float* conv_w = (const float*)d_in[7];
  const float* conv_b = (const float*)d_in[8];
  const float* w_xp   = (const float*)d_in[9];
  const float* w_dt   = (const float*)d_in[10];
  const float* dt_bias= (const float*)d_in[11];
  const float* Amat   = (const float*)d_in[12];
  const float* Dvec   = (const float*)d_in[13];
  const float* w_out  = (const float*)d_in[14];
  float* out = (float*)d_out;

  char* ws = (char*)d_ws;
  const size_t MiB = (size_t)1 << 20;

  unsigned short *hs_b, *w_in_b, *x_b, *z_b, *u_b, *delta_b;
  unsigned short *wxp_b, *wdt_b, *wout_b, *dtr_b, *y_b;
  float *xdbl, *Sbuf, *Xin, *sdelta, *xpart;

  if (ws_size >= 424*MiB){
    size_t off = 0;
    auto alloc = [&](size_t bytes)->void*{ void* p = ws + off; off += (bytes + 255) & ~(size_t)255; return p; };
    hs_b   = (unsigned short*)alloc((size_t)MROWS*DMODEL*2);
    w_in_b = (unsigned short*)alloc((size_t)2*DINNER*DMODEL*2);
    x_b    = (unsigned short*)alloc((size_t)MROWS*DINNER*2);
    z_b    = (unsigned short*)alloc((size_t)MROWS*DINNER*2);
    u_b    = (unsigned short*)alloc((size_t)MROWS*DINNER*2);
    delta_b= (unsigned short*)alloc((size_t)MROWS*DINNER*2);
    wxp_b  = (unsigned short*)alloc((size_t)160*DINNER*2);
    wdt_b  = (unsigned short*)alloc((size_t)DINNER*DTRANK*2);
    wout_b = (unsigned short*)alloc((size_t)DMODEL*DINNER*2);
    xdbl   = (float*)alloc((size_t)MROWS*160*4);
    dtr_b  = (unsigned short*)alloc((size_t)MROWS*DTRANK*2);
    Sbuf   = (float*)alloc((size_t)NB*NCHUNK*DSTATE*DINNER*4);
    Xin    = (float*)alloc((size_t)NB*NCHUNK*DSTATE*DINNER*4);
    sdelta = (float*)alloc((size_t)NB*NCHUNK*DINNER*4);
    xpart  = (float*)alloc((size_t)4*MROWS*160*4);
    y_b    = x_b;
  } else {
    hs_b    = (unsigned short*)(ws + 0);
    w_in_b  = (unsigned short*)(ws + 32*MiB);
    xpart   = (float*)         (ws + 0);   // steps 6-7 (hs/w_in dead)
    delta_b = (unsigned short*)(ws + 0);   // step 8+ (xpart dead)
    x_b     = (unsigned short*)(ws + 64*MiB);
    wxp_b   = (unsigned short*)(ws + 64*MiB);
    wdt_b   = (unsigned short*)(ws + 66*MiB);
    wout_b  = (unsigned short*)(ws + 68*MiB);
    xdbl    = (float*)         (ws + 84*MiB);
    dtr_b   = (unsigned short*)(ws + 90*MiB);
    Sbuf    = (float*)         (ws + 92*MiB);
    Xin     = (float*)         (ws + 108*MiB);
    sdelta  = (float*)         (ws + 124*MiB);
    z_b     = (unsigned short*)(ws + 128*MiB);
    u_b     = (unsigned short*)(ws + 192*MiB);
    y_b     = u_b;
  }

  // 1) converts needed for in_proj
  cvt_bf16_kernel<<<(MROWS*DMODEL)/1024, 256, 0, stream>>>(hs, hs_b, MROWS*DMODEL);
  cvt_bf16_kernel<<<(2*DINNER*DMODEL)/1024, 256, 0, stream>>>(w_in, w_in_b, 2*DINNER*DMODEL);

  // 2) in_proj: (8192x2048)@(8192x2048)^T, 256^2 tiles -> 32x32=1024 blocks
  gemm256<0><<<1024, 512, 0, stream>>>(hs_b, w_in_b, DMODEL, 32, 0,
                                       x_b, z_b, nullptr);
  // 3) new_conv_state
  conv_state_kernel<<<256, 256, 0, stream>>>(x_b, out + (size_t)MROWS*DMODEL);
  // 4) conv + silu -> u (x dead afterwards)
  conv_silu_kernel<<<(MROWS*512)/256, 256, 0, stream>>>(x_b, conv_w, conv_b, u_b);

  // 5) weight converts (into dead-x slot in aliased mode)
  cvt_bf16_kernel<<<(160*DINNER)/1024, 256, 0, stream>>>(w_xp, wxp_b, 160*DINNER);
  cvt_bf16_kernel<<<(DINNER*DTRANK)/1024, 256, 0, stream>>>(w_dt, wdt_b, DINNER*DTRANK);
  cvt_bf16_kernel<<<(DMODEL*DINNER)/1024, 256, 0, stream>>>(w_out, wout_b, DMODEL*DINNER);

  // 6) x_proj split-K x4 -> partials (512 blocks instead of 128)
  gemm_bt<4><<<dim3(2,64,4), 256, 0, stream>>>(u_b, wxp_b, DINNER, 1024, 160,
                                               xpart, nullptr, nullptr, 160);
  // 7) reduce partials -> xdbl fp32 + dtr bf16
  reduce_xproj<<<(MROWS*160/4)/256, 256, 0, stream>>>(xpart, xdbl, dtr_b);
  // 8) dt_proj + softplus -> delta
  gemm_bt<2><<<dim3(32,64), 256, 0, stream>>>(dtr_b, wdt_b, DTRANK, DTRANK, DINNER,
                                              nullptr, delta_b, dt_bias, DINNER);
  // 9) chunked scan
  scan_part1<<<1024, 256, 0, stream>>>(delta_b, u_b, xdbl, Amat, Sbuf, sdelta);
  scan_part2<<<1024, 256, 0, stream>>>(Sbuf, sdelta, Amat, Xin,
                                       out + (size_t)MROWS*DMODEL + NB*DINNER*4);
  scan_part3<<<1024, 256, 0, stream>>>(delta_b, u_b, z_b, xdbl, Amat, Dvec, Xin, y_b);
  // 10) out_proj: (8192x4096)@(2048x4096)^T, 32x8=256 blocks
  gemm256<3><<<256, 512, 0, stream>>>(y_b, wout_b, DINNER, 8, DMODEL,
                                      nullptr, nullptr, out);
}